// Round 1
// 283.704 us; speedup vs baseline: 1.1227x; 1.1227x over previous
//
#include <hip/hip_runtime.h>
#include <stdint.h>

// Problem constants
#define L_   3969         // patches
#define LP   3972         // padded L (mult of 4, for float4 loads)
#define EPS_ 1e-5f
#define LOG2E 1.4426950408889634f
#define MH   6            // split over im (patch-row chunks) in K3
#define IMR  11           // im rows per chunk (6*11 >= 63)

// workspace layout (float offsets). Total 6,720,608 floats = 26.9 MB
#define OFF_MF   0          // [2][64][LP] fg mean
#define OFF_SF   508416     // fg var
#define OFF_MB   1016832    // bg mean
#define OFF_SB   1525248    // bg var
#define OFF_TOKF 2033664    // [2 b][LP][64 c]; PART slice kc=0 (t=0 half)
#define OFF_TOKB 2542080    //                 PART slice kc=0 (t=1 half)
#define OFF_PACC 3050496    // [MH][2 b][LP][64]; also PART slices kc=1..3 (dead until k3)
#define OFF_PM   6100992    // [MH][2][LP]
#define OFF_PD   6148656
#define OFF_WT   6196320    // W2: bf16 frag-ordered weights (1M bf16)
#define PART_SLICE 1016832  // floats per kc slice: [2 t][2 b][LP][64]

typedef __attribute__((ext_vector_type(8))) short bf16x8;   // 8 bf16 (4 VGPRs)
typedef __attribute__((ext_vector_type(4))) float f32x4;    // MFMA accumulator

__device__ __forceinline__ uint16_t bf16_rne(float f) {
    uint32_t u = __float_as_uint(f);
    return (uint16_t)((u + 0x7FFFu + ((u >> 16) & 1u)) >> 16);
}
// hi = truncated top-16 bits (exact), lo = RNE(residual): hi+lo ~ 2^-17 relative
__device__ __forceinline__ void split_bf16(float v, uint16_t& h, uint16_t& l) {
    uint32_t u = __float_as_uint(v);
    uint32_t hu = u & 0xFFFF0000u;
    h = (uint16_t)(hu >> 16);
    l = bf16_rne(v - __uint_as_float(hu));
}
__device__ __forceinline__ uint4 pack8(const uint16_t* s) {
    uint4 r;
    r.x = (uint32_t)s[0] | ((uint32_t)s[1] << 16);
    r.y = (uint32_t)s[2] | ((uint32_t)s[3] << 16);
    r.z = (uint32_t)s[4] | ((uint32_t)s[5] << 16);
    r.w = (uint32_t)s[6] | ((uint32_t)s[7] << 16);
    return r;
}
// pair packers for the k2 fast path: elem a -> low16, elem b -> high16
__device__ __forceinline__ uint32_t pkhi2(float a, float b) {
    return (__float_as_uint(a) >> 16) | (__float_as_uint(b) & 0xFFFF0000u);
}
__device__ __forceinline__ uint32_t pklo2(float a, float b) {
    float ra = a - __uint_as_float(__float_as_uint(a) & 0xFFFF0000u);
    float rb = b - __uint_as_float(__float_as_uint(b) & 0xFFFF0000u);
    uint32_t r;
    asm("v_cvt_pk_bf16_f32 %0, %1, %2" : "=v"(r) : "v"(ra), "v"(rb));
    return r;
}

// ---------------- K0: weights -> split-bf16 MFMA A-fragment layout ----------------
__global__ void k0_w2(const float* __restrict__ wf, const float* __restrict__ wb,
                      float* __restrict__ ws) {
    int c = blockIdx.x, t = blockIdx.y;
    const float* w = t ? wb : wf;
    uint16_t* w2 = (uint16_t*)(ws + OFF_WT);
    int tid = threadIdx.x;
    int lane = tid & 63, dq = tid >> 6;
    int d = dq * 16 + (lane & 15), quad = lane >> 4;
    for (int kci = 0; kci < 2; ++kci) {
        int k = kci * 32 + quad * 8;
        const float* src = w + (size_t)(d * 64 + c) * 64 + k;
        uint16_t hb[8], lb[8];
#pragma unroll
        for (int j = 0; j < 8; ++j) split_bf16(src[j], hb[j], lb[j]);
        size_t base = ((size_t)(((t * 64 + c) * 2 + kci) * 4 + dq) * 2) * 512 + lane * 8;
        *(uint4*)(w2 + base) = pack8(hb);
        *(uint4*)(w2 + base + 512) = pack8(lb);
    }
}

// ---------------- K1: per-patch fg/bg stats ----------------
__global__ void k1_stats(const float* __restrict__ x, const float* __restrict__ mask,
                         float* __restrict__ ws) {
    int i = blockIdx.x, c = blockIdx.y, b = blockIdx.z;
    __shared__ float xs[8 * 256];
    __shared__ float ms[8 * 256];
    __shared__ float pS[5][256];
    int t = threadIdx.x;
    const float* xr = x + (((b * 64 + c) * 256) + i * 4) * 256;
    const float* mr = mask + (b * 256 + i * 4) * 256;
#pragma unroll
    for (int r = 0; r < 8; ++r) {
        xs[r * 256 + t] = xr[r * 256 + t];
        ms[r * 256 + t] = mr[r * 256 + t];
    }
    __syncthreads();
    int q = t >> 6, j = t & 63;
    float Sa = 0, Qa = 0, Sf = 0, Qf = 0, Nf = 0;
    if (j < 63) {
#pragma unroll
        for (int rr = 0; rr < 2; ++rr) {
            int base = (q * 2 + rr) * 256 + j * 4;
#pragma unroll
            for (int cc = 0; cc < 8; ++cc) {
                float v = xs[base + cc], m = ms[base + cc];
                Sa += v; Qa += v * v; Sf += v * m; Qf += v * v * m; Nf += m;
            }
        }
    }
    pS[0][t] = Sa; pS[1][t] = Qa; pS[2][t] = Sf; pS[3][t] = Qf; pS[4][t] = Nf;
    __syncthreads();
    if (q == 0 && j < 63) {
        Sa = pS[0][j] + pS[0][j + 64] + pS[0][j + 128] + pS[0][j + 192];
        Qa = pS[1][j] + pS[1][j + 64] + pS[1][j + 128] + pS[1][j + 192];
        Sf = pS[2][j] + pS[2][j + 64] + pS[2][j + 128] + pS[2][j + 192];
        Qf = pS[3][j] + pS[3][j + 64] + pS[3][j + 128] + pS[3][j + 192];
        Nf = pS[4][j] + pS[4][j + 64] + pS[4][j + 128] + pS[4][j + 192];
        float nb = 64.0f - Nf;
        float muf = Sf / (Nf + EPS_);
        float vaf = (Qf - 2.f * muf * Sf + Nf * muf * muf) / (Nf + EPS_);
        float Sb = Sa - Sf, Qb = Qa - Qf;
        float mub = Sb / (nb + EPS_);
        float vab = (Qb - 2.f * mub * Sb + nb * mub * mub) / (nb + EPS_);
        int idx = (b * 64 + c) * LP + i * 63 + j;
        ws[OFF_MF + idx] = muf; ws[OFF_SF + idx] = vaf;
        ws[OFF_MB + idx] = mub; ws[OFF_SB + idx] = vab;
    }
}

// ---------------- K2: split-bf16 MFMA tok GEMM ----------------
// Rewritten: single-channel double-buffered pipeline (1 barrier/channel),
// 2x2 wave->(d,l) tile split (halves redundant weight-fragment L2 traffic,
// 4x A-frag register reuse), cvt_pk-based packing (~2x fewer VALU ops).
// grid (63 il, 4 kc, 2 b), 256 threads. LDS 72 KB -> 2 blocks/CU.
__global__ __launch_bounds__(256)
void k2_tok(const float* __restrict__ x, const float* __restrict__ mask,
            const float* __restrict__ wsc, float* __restrict__ ws) {
    int il = blockIdx.x, kc = blockIdx.y, b = blockIdx.z;
    int tid = threadIdx.x;
    int jl = tid & 63;
    int q = tid >> 6;
    __shared__ uint16_t IN[2][4 * 64 * 72];   // [buffer][plane 4][l 64][k 72pad]
    const uint16_t* w2 = (const uint16_t*)(wsc + OFF_WT);

    bool lv = jl < 63;
    int lg = il * 63 + jl;

    uint32_t mbits[2] = {0u, 0u};
    if (lv) {
#pragma unroll
        for (int oi = 0; oi < 2; ++oi) {
            int o = q + oi * 4;
            const float* mp = mask + (size_t)b * 65536 + (il * 4 + o) * 256 + jl * 4;
            float4 m0 = *(const float4*)mp;
            float4 m1 = *(const float4*)(mp + 4);
            uint32_t bits = 0;
            bits |= (m0.x != 0.f) ? 1u : 0u;  bits |= (m0.y != 0.f) ? 2u : 0u;
            bits |= (m0.z != 0.f) ? 4u : 0u;  bits |= (m0.w != 0.f) ? 8u : 0u;
            bits |= (m1.x != 0.f) ? 16u : 0u; bits |= (m1.y != 0.f) ? 32u : 0u;
            bits |= (m1.z != 0.f) ? 64u : 0u; bits |= (m1.w != 0.f) ? 128u : 0u;
            mbits[oi] = bits;
        }
    }

    f32x4 acc[2][2][2];   // [t][dqi][lt]
#pragma unroll
    for (int t = 0; t < 2; ++t)
#pragma unroll
        for (int i2 = 0; i2 < 2; ++i2)
#pragma unroll
            for (int j2 = 0; j2 < 2; ++j2) acc[t][i2][j2] = (f32x4)(0.f);

    int lane = tid & 63;
    int quad = lane >> 4;
    int c16 = lane & 15;
    int wd = q >> 1, wl = q & 1;   // wave tile: d half, l half
    int c0 = kc * 16;

    // pipeline registers: one channel
    float4 xa[2][2];   // [oi][half]
    if (!lv) {
        xa[0][0] = xa[0][1] = xa[1][0] = xa[1][1] = make_float4(0.f, 0.f, 0.f, 0.f);
    }
    float muF = 0.f, vaF = 1.f, muB = 0.f, vaB = 1.f;

#define K2_LOADCH(cc)                                                                \
    do {                                                                             \
        if (lv) {                                                                    \
            int si = (b * 64 + (cc)) * LP + lg;                                      \
            muF = wsc[OFF_MF + si]; vaF = wsc[OFF_SF + si];                          \
            muB = wsc[OFF_MB + si]; vaB = wsc[OFF_SB + si];                          \
            const float* xp0 = x + (size_t)(b * 64 + (cc)) * 65536 + (il * 4 + q) * 256 + jl * 4; \
            xa[0][0] = *(const float4*)xp0;                                          \
            xa[0][1] = *(const float4*)(xp0 + 4);                                    \
            xa[1][0] = *(const float4*)(xp0 + 1024);                                 \
            xa[1][1] = *(const float4*)(xp0 + 1028);                                 \
        }                                                                            \
    } while (0)

    // pack current xa/stats into buffer 'bufsel'. For jl==63 lanes: mbits==0,
    // cmF/cmB/invF/invB == 0 and xa == 0 -> all staged values are exactly 0.
#define K2_PACKSTORE(bufsel)                                                         \
    do {                                                                             \
        float invF = lv ? (1.0f / vaF) : 0.f;                                        \
        float invB = lv ? (1.0f / vaB) : 0.f;                                        \
        float cmF = lv ? muF : 0.f;                                                  \
        float cmB = lv ? muB : 0.f;                                                  \
        _Pragma("unroll")                                                            \
        for (int oi = 0; oi < 2; ++oi) {                                             \
            float xv[8];                                                             \
            xv[0] = xa[oi][0].x; xv[1] = xa[oi][0].y;                                \
            xv[2] = xa[oi][0].z; xv[3] = xa[oi][0].w;                                \
            xv[4] = xa[oi][1].x; xv[5] = xa[oi][1].y;                                \
            xv[6] = xa[oi][1].z; xv[7] = xa[oi][1].w;                                \
            float fv[8], bv[8];                                                      \
            _Pragma("unroll")                                                        \
            for (int j = 0; j < 8; ++j) {                                            \
                bool mf = (mbits[oi] >> j) & 1;                                      \
                float v = xv[j];                                                     \
                fv[j] = mf ? (v - cmF) * invF : cmF;                                 \
                bv[j] = mf ? cmB : (v - cmB) * invB;                                 \
            }                                                                        \
            uint4 FH, FL, BH, BL;                                                    \
            FH.x = pkhi2(fv[0], fv[1]); FH.y = pkhi2(fv[2], fv[3]);                  \
            FH.z = pkhi2(fv[4], fv[5]); FH.w = pkhi2(fv[6], fv[7]);                  \
            FL.x = pklo2(fv[0], fv[1]); FL.y = pklo2(fv[2], fv[3]);                  \
            FL.z = pklo2(fv[4], fv[5]); FL.w = pklo2(fv[6], fv[7]);                  \
            BH.x = pkhi2(bv[0], bv[1]); BH.y = pkhi2(bv[2], bv[3]);                  \
            BH.z = pkhi2(bv[4], bv[5]); BH.w = pkhi2(bv[6], bv[7]);                  \
            BL.x = pklo2(bv[0], bv[1]); BL.y = pklo2(bv[2], bv[3]);                  \
            BL.z = pklo2(bv[4], bv[5]); BL.w = pklo2(bv[6], bv[7]);                  \
            uint16_t* dst = &IN[bufsel][jl * 72 + (q + oi * 4) * 8];                 \
            *(uint4*)(dst)         = FH;                                             \
            *(uint4*)(dst + 4608)  = FL;                                             \
            *(uint4*)(dst + 9216)  = BH;                                             \
            *(uint4*)(dst + 13824) = BL;                                             \
        }                                                                            \
    } while (0)

    // MFMA over one staged channel. Wave covers d in [wd*32, wd*32+32),
    // l in [wl*32, wl*32+32). A frags reused across both l-tiles.
#define K2_MFMA(bufi, cch)                                                           \
    do {                                                                             \
        _Pragma("unroll")                                                            \
        for (int t = 0; t < 2; ++t) {                                                \
            _Pragma("unroll")                                                        \
            for (int kci = 0; kci < 2; ++kci) {                                      \
                bf16x8 Ah[2], Al[2];                                                 \
                _Pragma("unroll")                                                    \
                for (int dqi = 0; dqi < 2; ++dqi) {                                  \
                    const uint16_t* ab = w2 +                                        \
                        ((size_t)(((t * 64 + (cch)) * 2 + kci) * 4 + (wd * 2 + dqi)) * 2) * 512 + lane * 8; \
                    Ah[dqi] = *(const bf16x8*)ab;                                    \
                    Al[dqi] = *(const bf16x8*)(ab + 512);                            \
                }                                                                    \
                _Pragma("unroll")                                                    \
                for (int lt = 0; lt < 2; ++lt) {                                     \
                    const uint16_t* bp = &IN[bufi][(t * 2) * 4608 +                  \
                        (wl * 32 + lt * 16 + c16) * 72 + kci * 32 + quad * 8];       \
                    bf16x8 Bh = *(const bf16x8*)bp;                                  \
                    bf16x8 Bl = *(const bf16x8*)(bp + 4608);                         \
                    _Pragma("unroll")                                                \
                    for (int dqi = 0; dqi < 2; ++dqi) {                              \
                        acc[t][dqi][lt] = __builtin_amdgcn_mfma_f32_16x16x32_bf16(Ah[dqi], Bh, acc[t][dqi][lt], 0, 0, 0); \
                        acc[t][dqi][lt] = __builtin_amdgcn_mfma_f32_16x16x32_bf16(Ah[dqi], Bl, acc[t][dqi][lt], 0, 0, 0); \
                        acc[t][dqi][lt] = __builtin_amdgcn_mfma_f32_16x16x32_bf16(Al[dqi], Bh, acc[t][dqi][lt], 0, 0, 0); \
                    }                                                                \
                }                                                                    \
            }                                                                        \
        }                                                                            \
    } while (0)

    // prologue: stage channel c0 into buffer 0, prefetch c0+1
    K2_LOADCH(c0);
    K2_PACKSTORE(0);
    K2_LOADCH(c0 + 1);
    __syncthreads();

    // steady state: one barrier per channel. Writes go to buffer cur^1 whose
    // readers all finished before the previous barrier; reads come from cur.
#pragma unroll 2
    for (int ci = 0; ci < 16; ++ci) {
        int cur = ci & 1;
        if (ci < 15) {
            K2_PACKSTORE(cur ^ 1);             // pack channel ci+1
            if (ci < 14) K2_LOADCH(c0 + ci + 2); // issue global loads for ci+2
        }
        K2_MFMA(cur, c0 + ci);
        __syncthreads();
    }
#undef K2_LOADCH
#undef K2_PACKSTORE
#undef K2_MFMA

    // ---- epilogue: LDS transpose -> coalesced float4 stores to PART (no atomics) ----
    // C/D 16x16: row(d within tile)=quad*4+r, col(l within tile)=lane&15
    float* ST = (float*)&IN[0][0];   // 64 l x 68 d floats = 17.4 KB, fits
#pragma unroll
    for (int t = 0; t < 2; ++t) {
        __syncthreads();
#pragma unroll
        for (int dqi = 0; dqi < 2; ++dqi)
#pragma unroll
            for (int lt = 0; lt < 2; ++lt)
#pragma unroll
                for (int r = 0; r < 4; ++r)
                    ST[(wl * 32 + lt * 16 + c16) * 68 + (wd * 2 + dqi) * 16 + quad * 4 + r] =
                        acc[t][dqi][lt][r];
        __syncthreads();
        float* dst = ws + OFF_TOKF + (size_t)kc * PART_SLICE + ((t * 2 + b) * (size_t)LP) * 64;
        int d4 = (tid & 15) * 4;
#pragma unroll
        for (int pass = 0; pass < 4; ++pass) {
            int l = pass * 16 + (tid >> 4);
            if (l < 63)
                *(float4*)&dst[(size_t)(il * 63 + l) * 64 + d4] = *(float4*)&ST[l * 68 + d4];
        }
    }
}

// ---------------- K2r: reduce 4 kc partial slices into slice 0 (= TOKF/TOKB) ----------------
__global__ void k2r_reduce(float* __restrict__ ws) {
    size_t i = ((size_t)blockIdx.x * 256 + threadIdx.x) * 4;
    float4 a0 = *(float4*)&ws[OFF_TOKF + i];
    float4 a1 = *(float4*)&ws[OFF_TOKF + PART_SLICE + i];
    float4 a2 = *(float4*)&ws[OFF_TOKF + 2 * PART_SLICE + i];
    float4 a3 = *(float4*)&ws[OFF_TOKF + 3 * PART_SLICE + i];
    a0.x += a1.x + a2.x + a3.x; a0.y += a1.y + a2.y + a3.y;
    a0.z += a1.z + a2.z + a3.z; a0.w += a1.w + a2.w + a3.w;
    *(float4*)&ws[OFF_TOKF + i] = a0;
}

// ---------------- K3: MFMA flash attention over patch-rows ----------------
// grid (63 il, MH imc, 2 b), 256 threads.
__global__ __launch_bounds__(256)
void k3_attn(const float* __restrict__ wsc, const float* __restrict__ rpb,
             float* __restrict__ ws) {
    int il = blockIdx.x, imc = blockIdx.y, b = blockIdx.z;
    int tid = threadIdx.x;
    int w = tid >> 6, lane = tid & 63;
    int c16 = lane & 15, quad = lane >> 4;

    __shared__ uint16_t TFh[64 * 72], TFl[64 * 72];   // tok_f [l][c] hi/lo
    __shared__ uint16_t TBh[64 * 72];                 // tok_b hi [m][c]; aliased as P [l][m]
    __shared__ uint16_t TBl[64 * 72];                 // tok_b lo
    __shared__ uint16_t SB[64 * 72];                  // sb [c][m] bf16
    __shared__ float bias_r[128];

    const float* TOKF = wsc + OFF_TOKF + (size_t)b * LP * 64;
    const float* TOKB = wsc + OFF_TOKB + (size_t)b * LP * 64;
    const float* SBg  = wsc + OFF_SB + (size_t)b * 64 * LP;   // [c][LP]

    {
        int jl = tid >> 2, cc = (tid & 3) * 16;
        bool v = jl < 63;
        const float* src = TOKF + (size_t)(il * 63 + jl) * 64 + cc;
        uint16_t hh[16], lo[16];
#pragma unroll
        for (int u = 0; u < 16; u += 4) {
            float4 f = v ? *(const float4*)(src + u) : make_float4(0.f, 0.f, 0.f, 0.f);
            split_bf16(f.x, hh[u], lo[u]);     split_bf16(f.y, hh[u + 1], lo[u + 1]);
            split_bf16(f.z, hh[u + 2], lo[u + 2]); split_bf16(f.w, hh[u + 3], lo[u + 3]);
        }
        *(uint4*)&TFh[jl * 72 + cc] = pack8(hh); *(uint4*)&TFh[jl * 72 + cc + 8] = pack8(hh + 8);
        *(uint4*)&TFl[jl * 72 + cc] = pack8(lo); *(uint4*)&TFl[jl * 72 + cc + 8] = pack8(lo + 8);
    }

    float mrun[4] = {-1e30f, -1e30f, -1e30f, -1e30f};
    float drun[4] = {0.f, 0.f, 0.f, 0.f};
    f32x4 acc2[4];
#pragma unroll
    for (int ct = 0; ct < 4; ++ct) acc2[ct] = (f32x4)(0.f);

    int im0 = imc * IMR;
    int im1 = min(63, im0 + IMR);
    for (int im = im0; im < im1; ++im) {
        __syncthreads();
        {
            int jm = tid >> 2, cc = (tid & 3) * 16;
            bool v = jm < 63;
            const float* src = TOKB + (size_t)(im * 63 + jm) * 64 + cc;
            uint16_t hh[16], lo[16];
#pragma unroll
            for (int u = 0; u < 16; u += 4) {
                float4 f = v ? *(const float4*)(src + u) : make_float4(0.f, 0.f, 0.f, 0.f);
                split_bf16(f.x, hh[u], lo[u]);     split_bf16(f.y, hh[u + 1], lo[u + 1]);
                split_bf16(f.z, hh[u + 2], lo[u + 2]); split_bf16(f.w, hh[u + 3], lo[u + 3]);
            }
            *(uint4*)&TBh[jm * 72 + cc] = pack8(hh); *(uint4*)&TBh[jm * 72 + cc + 8] = pack8(hh + 8);
            *(uint4*)&TBl[jm * 72 + cc] = pack8(lo); *(uint4*)&TBl[jm * 72 + cc + 8] = pack8(lo + 8);
        }
        {
            int c = tid >> 2, mm = (tid & 3) * 16;
            const float* src = SBg + (size_t)c * LP + im * 63 + mm;
            uint16_t sv[16];
#pragma unroll
            for (int u = 0; u < 16; ++u)
                sv[u] = (mm + u < 63) ? bf16_rne(src[u]) : (uint16_t)0;
            *(uint4*)&SB[c * 72 + mm] = pack8(sv); *(uint4*)&SB[c * 72 + mm + 8] = pack8(sv + 8);
        }
        if (tid < 125) bias_r[tid] = rpb[(il - im + 62) * 125 + tid];
        else if (tid < 128) bias_r[tid] = 0.f;
        __syncthreads();

        f32x4 Z[4];
#pragma unroll
        for (int jt = 0; jt < 4; ++jt) Z[jt] = (f32x4)(0.f);
#pragma unroll
        for (int kk = 0; kk < 2; ++kk) {
            bf16x8 Ah = *(bf16x8*)&TFh[(w * 16 + c16) * 72 + kk * 32 + quad * 8];
            bf16x8 Al = *(bf16x8*)&TFl[(w * 16 + c16) * 72 + kk * 32 + quad * 8];
#pragma unroll
            for (int jt = 0; jt < 4; ++jt) {
                bf16x8 Bh = *(bf16x8*)&TBh[(jt * 16 + c16) * 72 + kk * 32 + quad * 8];
                bf16x8 Bl = *(bf16x8*)&TBl[(jt * 16 + c16) * 72 + kk * 32 + quad * 8];
                Z[jt] = __builtin_amdgcn_mfma_f32_16x16x32_bf16(Ah, Bh, Z[jt], 0, 0, 0);
                Z[jt] = __builtin_amdgcn_mfma_f32_16x16x32_bf16(Ah, Bl, Z[jt], 0, 0, 0);
                Z[jt] = __builtin_amdgcn_mfma_f32_16x16x32_bf16(Al, Bh, Z[jt], 0, 0, 0);
            }
        }
        float zv[4][4];
#pragma unroll
        for (int jt = 0; jt < 4; ++jt) {
            int jm = jt * 16 + c16;
#pragma unroll
            for (int r = 0; r < 4; ++r) {
                int i = w * 16 + quad * 4 + r;
                zv[jt][r] = (jm == 63) ? -1e30f : (Z[jt][r] + bias_r[i - jm + 62]);
            }
        }
        float alphav[4];
        uint16_t pb[4][4];
#pragma unroll
        for (int r = 0; r < 4; ++r) {
            float v = fmaxf(fmaxf(zv[0][r], zv[1][r]), fmaxf(zv[2][r], zv[3][r]));
            v = fmaxf(v, __shfl_xor(v, 1));
            v = fmaxf(v, __shfl_xor(v, 2));
            v = fmaxf(v, __shfl_xor(v, 4));
            v = fmaxf(v, __shfl_xor(v, 8));
            float mnew = fmaxf(mrun[r], v);
            alphav[r] = exp2f((mrun[r] - mnew) * LOG2E);
            float s = 0.f;
#pragma unroll
            for (int jt = 0; jt < 4; ++jt) {
                float p = exp2f((zv[jt][r] - mnew) * LOG2E);
                uint16_t h = bf16_rne(p);
                pb[jt][r] = h;
                s += __uint_as_float((uint32_t)h << 16);
            }
            s += __shfl_xor(s, 1); s += __shfl_xor(s, 2);
            s += __shfl_xor(s, 4); s += __shfl_xor(s, 8);
            drun[r] = drun[r] * alphav[r] + s;
            mrun[r] = mnew;
        }
#pragma unroll
        for (int ct = 0; ct < 4; ++ct)
#pragma unroll
            for (int r = 0; r < 4; ++r) acc2[ct][r] *= alphav[r];

        __syncthreads();
#pragma unroll
        for (int jt = 0; jt < 4; ++jt)
#pragma unroll
            for (int r = 0; r < 4; ++r)
                TBh[(w * 16 + quad * 4 + r) * 72 + jt * 16 + c16] = pb[jt][r];
        __syncthreads();

#pragma unroll
        for (int kk = 0; kk < 2; ++kk) {
            bf16x8 Pf = *(bf16x8*)&TBh[(w * 16 + c16) * 72 + kk * 32 + quad * 8];
#pragma unroll
            for (int ct = 0; ct < 4; ++ct) {
                bf16x8 Sf = *(bf16x8*)&SB[(ct * 16 + c16) * 72 + kk * 32 + quad * 8];
                acc2[ct] = __builtin_amdgcn_mfma_f32_16x16x32_bf16(Pf, Sf, acc2[ct], 0, 0, 0);
            }
        }
    }
    float* PA = ws + OFF_PACC + ((imc * 2 + b) * (size_t)LP) * 64;
#pragma unroll
    for (int r = 0; r < 4; ++r) {
        int i = w * 16 + quad * 4 + r;
        if (i < 63) {
            int rl = il * 63 + i;
#pragma unroll
            for (int ct = 0; ct < 4; ++ct)
                PA[(size_t)rl * 64 + ct * 16 + c16] = acc2[ct][r];
            if (c16 == 0) {
                ws[OFF_PM + (imc * 2 + b) * LP + rl] = mrun[r];
                ws[OFF_PD + (imc * 2 + b) * LP + rl] = drun[r];
            }
        }
    }
}

// ---------------- K3b: merge the MH m-slices; result lands in PACC slice 0 ----------------
__global__ void k3b_merge(float* __restrict__ ws) {
    int b = blockIdx.y;
    int l = blockIdx.x * 4 + (threadIdx.x >> 6);
    int c = threadIdx.x & 63;
    if (l >= L_) return;
    float M = -1e30f;
#pragma unroll
    for (int p = 0; p < MH; ++p)
        M = fmaxf(M, ws[OFF_PM + (p * 2 + b) * LP + l]);
    float denom = 0.f, num = 0.f;
#pragma unroll
    for (int p = 0; p < MH; ++p) {
        float w = exp2f((ws[OFF_PM + (p * 2 + b) * LP + l] - M) * LOG2E);
        denom += ws[OFF_PD + (p * 2 + b) * LP + l] * w;
        num += ws[OFF_PACC + ((p * 2 + b) * (size_t)LP + l) * 64 + c] * w;
    }
    ws[OFF_PACC + (b * (size_t)LP + l) * 64 + c] = num / denom;
}

// ---------------- K4: fold + affines + compose output ----------------
__global__ void k4_fold(const float* __restrict__ x, const float* __restrict__ mask,
                        const float* __restrict__ fg_g, const float* __restrict__ fg_b,
                        const float* __restrict__ bg_g, const float* __restrict__ bg_b,
                        const float* __restrict__ wsc, float* __restrict__ out) {
    int gid = blockIdx.x * 256 + threadIdx.x;
    int col = gid & 255, r = (gid >> 8) & 255, c = (gid >> 16) & 63, b = gid >> 22;
    float xv = x[gid];
    float m = mask[b * 65536 + r * 256 + col];
    int imin = (r >= 4) ? ((r - 4) >> 2) : 0;
    int imax = min(62, r >> 2);
    int jmin = (col >= 4) ? ((col - 4) >> 2) : 0;
    int jmax = min(62, col >> 2);
    const float* MF = wsc + OFF_MF + (b * 64 + c) * LP;
    const float* SF = wsc + OFF_SF + (b * 64 + c) * LP;
    const float* NS = wsc + OFF_PACC + b * (size_t)LP * 64;  // merged NSTD (slice 0)
    float folded = 0.f;
    int cnt = (imax - imin + 1) * (jmax - jmin + 1);
    for (int i = imin; i <= imax; ++i)
        for (int j = jmin; j <= jmax; ++j) {
            int l = i * 63 + j;
            float mf = MF[l], sf = SF[l];
            float inf_ = (m != 0.f) ? (xv - mf) / sf : mf;
            folded += NS[l * 64 + c] * (inf_ + 1.f);
        }
    float invm = 1.f - m;
    float ub = (xv * invm * (1.f + bg_g[c]) + bg_b[c]) * invm;
    float nf = (folded / (float)cnt * (1.f + fg_g[c]) + fg_b[c]) * m;
    out[gid] = nf + ub;
}

extern "C" void kernel_launch(void* const* d_in, const int* in_sizes, int n_in,
                              void* d_out, int out_size, void* d_ws, size_t ws_size,
                              hipStream_t stream) {
    const float* x    = (const float*)d_in[0];
    const float* mask = (const float*)d_in[1];
    const float* fg_g = (const float*)d_in[2];
    const float* fg_b = (const float*)d_in[3];
    const float* bg_g = (const float*)d_in[4];
    const float* bg_b = (const float*)d_in[5];
    const float* wf   = (const float*)d_in[6];
    const float* wb   = (const float*)d_in[7];
    const float* rpb  = (const float*)d_in[8];
    float* ws = (float*)d_ws;
    float* out = (float*)d_out;

    k0_w2<<<dim3(64, 2), 256, 0, stream>>>(wf, wb, ws);
    k1_stats<<<dim3(63, 64, 2), 256, 0, stream>>>(x, mask, ws);
    k2_tok<<<dim3(63, 4, 2), 256, 0, stream>>>(x, mask, ws, ws);
    k2r_reduce<<<dim3(993), 256, 0, stream>>>(ws);
    k3_attn<<<dim3(63, MH, 2), 256, 0, stream>>>(ws, rpb, ws);
    k3b_merge<<<dim3(993, 2), 256, 0, stream>>>(ws);
    k4_fold<<<dim3(32768), 256, 0, stream>>>(x, mask, fg_g, fg_b, bg_g, bg_b, ws, out);
}

// Round 2
// 262.671 us; speedup vs baseline: 1.2126x; 1.0801x over previous
//
#include <hip/hip_runtime.h>
#include <stdint.h>

// Problem constants
#define L_   3969         // patches
#define LP   3972         // padded L (mult of 4, for float4 loads)
#define EPS_ 1e-5f
#define LOG2E 1.4426950408889634f
#define MH   6            // split over im (patch-row chunks) in K3
#define IMR  11           // im rows per chunk (6*11 >= 63)

// workspace layout (float offsets). Total 6,720,608 floats = 26.9 MB
#define OFF_MF   0          // [2][64][LP] fg mean
#define OFF_SF   508416     // fg var
#define OFF_MB   1016832    // bg mean
#define OFF_SB   1525248    // bg var
#define OFF_TOKF 2033664    // [2 b][LP][64 c]; PART slice kc=0 (t=0 half)
#define OFF_TOKB 2542080    //                 PART slice kc=0 (t=1 half)
#define OFF_PACC 3050496    // [MH][2 b][LP][64]; also PART slices kc=1..3 (dead until k3)
#define OFF_PM   6100992    // [MH][2][LP]
#define OFF_PD   6148656
#define OFF_WT   6196320    // W2: bf16 frag-ordered weights (1M bf16)
#define PART_SLICE 1016832  // floats per kc slice: [2 t][2 b][LP][64]

// fold coefficients (written by k3c AFTER k3b; these regions are dead by then)
#define OFF_A    2033664    // = OFF_TOKF  [2 b][64 c][LP]
#define OFF_B    2542080    // = OFF_TOKB
#define OFF_C    4067328    // = OFF_PACC + 2*508416 (PACC p=2 slice, dead after k3b)

typedef __attribute__((ext_vector_type(8))) short bf16x8;   // 8 bf16 (4 VGPRs)
typedef __attribute__((ext_vector_type(4))) float f32x4;    // MFMA accumulator

__device__ __forceinline__ uint16_t bf16_rne(float f) {
    uint32_t u = __float_as_uint(f);
    return (uint16_t)((u + 0x7FFFu + ((u >> 16) & 1u)) >> 16);
}
// hi = truncated top-16 bits (exact), lo = RNE(residual): hi+lo ~ 2^-17 relative
__device__ __forceinline__ void split_bf16(float v, uint16_t& h, uint16_t& l) {
    uint32_t u = __float_as_uint(v);
    uint32_t hu = u & 0xFFFF0000u;
    h = (uint16_t)(hu >> 16);
    l = bf16_rne(v - __uint_as_float(hu));
}
__device__ __forceinline__ uint4 pack8(const uint16_t* s) {
    uint4 r;
    r.x = (uint32_t)s[0] | ((uint32_t)s[1] << 16);
    r.y = (uint32_t)s[2] | ((uint32_t)s[3] << 16);
    r.z = (uint32_t)s[4] | ((uint32_t)s[5] << 16);
    r.w = (uint32_t)s[6] | ((uint32_t)s[7] << 16);
    return r;
}
// pair packers for the k2 fast path: elem a -> low16, elem b -> high16
__device__ __forceinline__ uint32_t pkhi2(float a, float b) {
    return (__float_as_uint(a) >> 16) | (__float_as_uint(b) & 0xFFFF0000u);
}
__device__ __forceinline__ uint32_t pklo2(float a, float b) {
    float ra = a - __uint_as_float(__float_as_uint(a) & 0xFFFF0000u);
    float rb = b - __uint_as_float(__float_as_uint(b) & 0xFFFF0000u);
    uint32_t r;
    asm("v_cvt_pk_bf16_f32 %0, %1, %2" : "=v"(r) : "v"(ra), "v"(rb));
    return r;
}

// ---------------- K0: weights -> split-bf16 MFMA A-fragment layout ----------------
__global__ void k0_w2(const float* __restrict__ wf, const float* __restrict__ wb,
                      float* __restrict__ ws) {
    int c = blockIdx.x, t = blockIdx.y;
    const float* w = t ? wb : wf;
    uint16_t* w2 = (uint16_t*)(ws + OFF_WT);
    int tid = threadIdx.x;
    int lane = tid & 63, dq = tid >> 6;
    int d = dq * 16 + (lane & 15), quad = lane >> 4;
    for (int kci = 0; kci < 2; ++kci) {
        int k = kci * 32 + quad * 8;
        const float* src = w + (size_t)(d * 64 + c) * 64 + k;
        uint16_t hb[8], lb[8];
#pragma unroll
        for (int j = 0; j < 8; ++j) split_bf16(src[j], hb[j], lb[j]);
        size_t base = ((size_t)(((t * 64 + c) * 2 + kci) * 4 + dq) * 2) * 512 + lane * 8;
        *(uint4*)(w2 + base) = pack8(hb);
        *(uint4*)(w2 + base + 512) = pack8(lb);
    }
}

// ---------------- K1: per-patch fg/bg stats ----------------
__global__ void k1_stats(const float* __restrict__ x, const float* __restrict__ mask,
                         float* __restrict__ ws) {
    int i = blockIdx.x, c = blockIdx.y, b = blockIdx.z;
    __shared__ float xs[8 * 256];
    __shared__ float ms[8 * 256];
    __shared__ float pS[5][256];
    int t = threadIdx.x;
    const float* xr = x + (((b * 64 + c) * 256) + i * 4) * 256;
    const float* mr = mask + (b * 256 + i * 4) * 256;
#pragma unroll
    for (int r = 0; r < 8; ++r) {
        xs[r * 256 + t] = xr[r * 256 + t];
        ms[r * 256 + t] = mr[r * 256 + t];
    }
    __syncthreads();
    int q = t >> 6, j = t & 63;
    float Sa = 0, Qa = 0, Sf = 0, Qf = 0, Nf = 0;
    if (j < 63) {
#pragma unroll
        for (int rr = 0; rr < 2; ++rr) {
            int base = (q * 2 + rr) * 256 + j * 4;
#pragma unroll
            for (int cc = 0; cc < 8; ++cc) {
                float v = xs[base + cc], m = ms[base + cc];
                Sa += v; Qa += v * v; Sf += v * m; Qf += v * v * m; Nf += m;
            }
        }
    }
    pS[0][t] = Sa; pS[1][t] = Qa; pS[2][t] = Sf; pS[3][t] = Qf; pS[4][t] = Nf;
    __syncthreads();
    if (q == 0 && j < 63) {
        Sa = pS[0][j] + pS[0][j + 64] + pS[0][j + 128] + pS[0][j + 192];
        Qa = pS[1][j] + pS[1][j + 64] + pS[1][j + 128] + pS[1][j + 192];
        Sf = pS[2][j] + pS[2][j + 64] + pS[2][j + 128] + pS[2][j + 192];
        Qf = pS[3][j] + pS[3][j + 64] + pS[3][j + 128] + pS[3][j + 192];
        Nf = pS[4][j] + pS[4][j + 64] + pS[4][j + 128] + pS[4][j + 192];
        float nb = 64.0f - Nf;
        float muf = Sf / (Nf + EPS_);
        float vaf = (Qf - 2.f * muf * Sf + Nf * muf * muf) / (Nf + EPS_);
        float Sb = Sa - Sf, Qb = Qa - Qf;
        float mub = Sb / (nb + EPS_);
        float vab = (Qb - 2.f * mub * Sb + nb * mub * mub) / (nb + EPS_);
        int idx = (b * 64 + c) * LP + i * 63 + j;
        ws[OFF_MF + idx] = muf; ws[OFF_SF + idx] = vaf;
        ws[OFF_MB + idx] = mub; ws[OFF_SB + idx] = vab;
    }
}

// ---------------- K2: split-bf16 MFMA tok GEMM ----------------
// Single-channel double-buffered pipeline (1 barrier/channel),
// 2x2 wave->(d,l) tile split, cvt_pk-based packing.
// grid (63 il, 4 kc, 2 b), 256 threads. LDS 72 KB -> 2 blocks/CU.
__global__ __launch_bounds__(256)
void k2_tok(const float* __restrict__ x, const float* __restrict__ mask,
            const float* __restrict__ wsc, float* __restrict__ ws) {
    int il = blockIdx.x, kc = blockIdx.y, b = blockIdx.z;
    int tid = threadIdx.x;
    int jl = tid & 63;
    int q = tid >> 6;
    __shared__ uint16_t IN[2][4 * 64 * 72];   // [buffer][plane 4][l 64][k 72pad]
    const uint16_t* w2 = (const uint16_t*)(wsc + OFF_WT);

    bool lv = jl < 63;
    int lg = il * 63 + jl;

    uint32_t mbits[2] = {0u, 0u};
    if (lv) {
#pragma unroll
        for (int oi = 0; oi < 2; ++oi) {
            int o = q + oi * 4;
            const float* mp = mask + (size_t)b * 65536 + (il * 4 + o) * 256 + jl * 4;
            float4 m0 = *(const float4*)mp;
            float4 m1 = *(const float4*)(mp + 4);
            uint32_t bits = 0;
            bits |= (m0.x != 0.f) ? 1u : 0u;  bits |= (m0.y != 0.f) ? 2u : 0u;
            bits |= (m0.z != 0.f) ? 4u : 0u;  bits |= (m0.w != 0.f) ? 8u : 0u;
            bits |= (m1.x != 0.f) ? 16u : 0u; bits |= (m1.y != 0.f) ? 32u : 0u;
            bits |= (m1.z != 0.f) ? 64u : 0u; bits |= (m1.w != 0.f) ? 128u : 0u;
            mbits[oi] = bits;
        }
    }

    f32x4 acc[2][2][2];   // [t][dqi][lt]
#pragma unroll
    for (int t = 0; t < 2; ++t)
#pragma unroll
        for (int i2 = 0; i2 < 2; ++i2)
#pragma unroll
            for (int j2 = 0; j2 < 2; ++j2) acc[t][i2][j2] = (f32x4)(0.f);

    int lane = tid & 63;
    int quad = lane >> 4;
    int c16 = lane & 15;
    int wd = q >> 1, wl = q & 1;   // wave tile: d half, l half
    int c0 = kc * 16;

    // pipeline registers: one channel
    float4 xa[2][2];   // [oi][half]
    if (!lv) {
        xa[0][0] = xa[0][1] = xa[1][0] = xa[1][1] = make_float4(0.f, 0.f, 0.f, 0.f);
    }
    float muF = 0.f, vaF = 1.f, muB = 0.f, vaB = 1.f;

#define K2_LOADCH(cc)                                                                \
    do {                                                                             \
        if (lv) {                                                                    \
            int si = (b * 64 + (cc)) * LP + lg;                                      \
            muF = wsc[OFF_MF + si]; vaF = wsc[OFF_SF + si];                          \
            muB = wsc[OFF_MB + si]; vaB = wsc[OFF_SB + si];                          \
            const float* xp0 = x + (size_t)(b * 64 + (cc)) * 65536 + (il * 4 + q) * 256 + jl * 4; \
            xa[0][0] = *(const float4*)xp0;                                          \
            xa[0][1] = *(const float4*)(xp0 + 4);                                    \
            xa[1][0] = *(const float4*)(xp0 + 1024);                                 \
            xa[1][1] = *(const float4*)(xp0 + 1028);                                 \
        }                                                                            \
    } while (0)

    // pack current xa/stats into buffer 'bufsel'. For jl==63 lanes: mbits==0,
    // cmF/cmB/invF/invB == 0 and xa == 0 -> all staged values are exactly 0.
#define K2_PACKSTORE(bufsel)                                                         \
    do {                                                                             \
        float invF = lv ? (1.0f / vaF) : 0.f;                                        \
        float invB = lv ? (1.0f / vaB) : 0.f;                                        \
        float cmF = lv ? muF : 0.f;                                                  \
        float cmB = lv ? muB : 0.f;                                                  \
        _Pragma("unroll")                                                            \
        for (int oi = 0; oi < 2; ++oi) {                                             \
            float xv[8];                                                             \
            xv[0] = xa[oi][0].x; xv[1] = xa[oi][0].y;                                \
            xv[2] = xa[oi][0].z; xv[3] = xa[oi][0].w;                                \
            xv[4] = xa[oi][1].x; xv[5] = xa[oi][1].y;                                \
            xv[6] = xa[oi][1].z; xv[7] = xa[oi][1].w;                                \
            float fv[8], bv[8];                                                      \
            _Pragma("unroll")                                                        \
            for (int j = 0; j < 8; ++j) {                                            \
                bool mf = (mbits[oi] >> j) & 1;                                      \
                float v = xv[j];                                                     \
                fv[j] = mf ? (v - cmF) * invF : cmF;                                 \
                bv[j] = mf ? cmB : (v - cmB) * invB;                                 \
            }                                                                        \
            uint4 FH, FL, BH, BL;                                                    \
            FH.x = pkhi2(fv[0], fv[1]); FH.y = pkhi2(fv[2], fv[3]);                  \
            FH.z = pkhi2(fv[4], fv[5]); FH.w = pkhi2(fv[6], fv[7]);                  \
            FL.x = pklo2(fv[0], fv[1]); FL.y = pklo2(fv[2], fv[3]);                  \
            FL.z = pklo2(fv[4], fv[5]); FL.w = pklo2(fv[6], fv[7]);                  \
            BH.x = pkhi2(bv[0], bv[1]); BH.y = pkhi2(bv[2], bv[3]);                  \
            BH.z = pkhi2(bv[4], bv[5]); BH.w = pkhi2(bv[6], bv[7]);                  \
            BL.x = pklo2(bv[0], bv[1]); BL.y = pklo2(bv[2], bv[3]);                  \
            BL.z = pklo2(bv[4], bv[5]); BL.w = pklo2(bv[6], bv[7]);                  \
            uint16_t* dst = &IN[bufsel][jl * 72 + (q + oi * 4) * 8];                 \
            *(uint4*)(dst)         = FH;                                             \
            *(uint4*)(dst + 4608)  = FL;                                             \
            *(uint4*)(dst + 9216)  = BH;                                             \
            *(uint4*)(dst + 13824) = BL;                                             \
        }                                                                            \
    } while (0)

    // MFMA over one staged channel. Wave covers d in [wd*32, wd*32+32),
    // l in [wl*32, wl*32+32). A frags reused across both l-tiles.
#define K2_MFMA(bufi, cch)                                                           \
    do {                                                                             \
        _Pragma("unroll")                                                            \
        for (int t = 0; t < 2; ++t) {                                                \
            _Pragma("unroll")                                                        \
            for (int kci = 0; kci < 2; ++kci) {                                      \
                bf16x8 Ah[2], Al[2];                                                 \
                _Pragma("unroll")                                                    \
                for (int dqi = 0; dqi < 2; ++dqi) {                                  \
                    const uint16_t* ab = w2 +                                        \
                        ((size_t)(((t * 64 + (cch)) * 2 + kci) * 4 + (wd * 2 + dqi)) * 2) * 512 + lane * 8; \
                    Ah[dqi] = *(const bf16x8*)ab;                                    \
                    Al[dqi] = *(const bf16x8*)(ab + 512);                            \
                }                                                                    \
                _Pragma("unroll")                                                    \
                for (int lt = 0; lt < 2; ++lt) {                                     \
                    const uint16_t* bp = &IN[bufi][(t * 2) * 4608 +                  \
                        (wl * 32 + lt * 16 + c16) * 72 + kci * 32 + quad * 8];       \
                    bf16x8 Bh = *(const bf16x8*)bp;                                  \
                    bf16x8 Bl = *(const bf16x8*)(bp + 4608);                         \
                    _Pragma("unroll")                                                \
                    for (int dqi = 0; dqi < 2; ++dqi) {                              \
                        acc[t][dqi][lt] = __builtin_amdgcn_mfma_f32_16x16x32_bf16(Ah[dqi], Bh, acc[t][dqi][lt], 0, 0, 0); \
                        acc[t][dqi][lt] = __builtin_amdgcn_mfma_f32_16x16x32_bf16(Ah[dqi], Bl, acc[t][dqi][lt], 0, 0, 0); \
                        acc[t][dqi][lt] = __builtin_amdgcn_mfma_f32_16x16x32_bf16(Al[dqi], Bh, acc[t][dqi][lt], 0, 0, 0); \
                    }                                                                \
                }                                                                    \
            }                                                                        \
        }                                                                            \
    } while (0)

    // prologue: stage channel c0 into buffer 0, prefetch c0+1
    K2_LOADCH(c0);
    K2_PACKSTORE(0);
    K2_LOADCH(c0 + 1);
    __syncthreads();

    // steady state: one barrier per channel. Writes go to buffer cur^1 whose
    // readers all finished before the previous barrier; reads come from cur.
#pragma unroll 2
    for (int ci = 0; ci < 16; ++ci) {
        int cur = ci & 1;
        if (ci < 15) {
            K2_PACKSTORE(cur ^ 1);             // pack channel ci+1
            if (ci < 14) K2_LOADCH(c0 + ci + 2); // issue global loads for ci+2
        }
        K2_MFMA(cur, c0 + ci);
        __syncthreads();
    }
#undef K2_LOADCH
#undef K2_PACKSTORE
#undef K2_MFMA

    // ---- epilogue: LDS transpose -> coalesced float4 stores to PART (no atomics) ----
    // C/D 16x16: row(d within tile)=quad*4+r, col(l within tile)=lane&15
    float* ST = (float*)&IN[0][0];   // 64 l x 68 d floats = 17.4 KB, fits
#pragma unroll
    for (int t = 0; t < 2; ++t) {
        __syncthreads();
#pragma unroll
        for (int dqi = 0; dqi < 2; ++dqi)
#pragma unroll
            for (int lt = 0; lt < 2; ++lt)
#pragma unroll
                for (int r = 0; r < 4; ++r)
                    ST[(wl * 32 + lt * 16 + c16) * 68 + (wd * 2 + dqi) * 16 + quad * 4 + r] =
                        acc[t][dqi][lt][r];
        __syncthreads();
        float* dst = ws + OFF_TOKF + (size_t)kc * PART_SLICE + ((t * 2 + b) * (size_t)LP) * 64;
        int d4 = (tid & 15) * 4;
#pragma unroll
        for (int pass = 0; pass < 4; ++pass) {
            int l = pass * 16 + (tid >> 4);
            if (l < 63)
                *(float4*)&dst[(size_t)(il * 63 + l) * 64 + d4] = *(float4*)&ST[l * 68 + d4];
        }
    }
}

// ---------------- K2r: reduce 4 kc partial slices into slice 0 (= TOKF/TOKB) ----------------
__global__ void k2r_reduce(float* __restrict__ ws) {
    size_t i = ((size_t)blockIdx.x * 256 + threadIdx.x) * 4;
    float4 a0 = *(float4*)&ws[OFF_TOKF + i];
    float4 a1 = *(float4*)&ws[OFF_TOKF + PART_SLICE + i];
    float4 a2 = *(float4*)&ws[OFF_TOKF + 2 * PART_SLICE + i];
    float4 a3 = *(float4*)&ws[OFF_TOKF + 3 * PART_SLICE + i];
    a0.x += a1.x + a2.x + a3.x; a0.y += a1.y + a2.y + a3.y;
    a0.z += a1.z + a2.z + a3.z; a0.w += a1.w + a2.w + a3.w;
    *(float4*)&ws[OFF_TOKF + i] = a0;
}

// ---------------- K3: MFMA flash attention over patch-rows ----------------
// grid (63 il, MH imc, 2 b), 256 threads.
__global__ __launch_bounds__(256)
void k3_attn(const float* __restrict__ wsc, const float* __restrict__ rpb,
             float* __restrict__ ws) {
    int il = blockIdx.x, imc = blockIdx.y, b = blockIdx.z;
    int tid = threadIdx.x;
    int w = tid >> 6, lane = tid & 63;
    int c16 = lane & 15, quad = lane >> 4;

    __shared__ uint16_t TFh[64 * 72], TFl[64 * 72];   // tok_f [l][c] hi/lo
    __shared__ uint16_t TBh[64 * 72];                 // tok_b hi [m][c]; aliased as P [l][m]
    __shared__ uint16_t TBl[64 * 72];                 // tok_b lo
    __shared__ uint16_t SB[64 * 72];                  // sb [c][m] bf16
    __shared__ float bias_r[128];

    const float* TOKF = wsc + OFF_TOKF + (size_t)b * LP * 64;
    const float* TOKB = wsc + OFF_TOKB + (size_t)b * LP * 64;
    const float* SBg  = wsc + OFF_SB + (size_t)b * 64 * LP;   // [c][LP]

    {
        int jl = tid >> 2, cc = (tid & 3) * 16;
        bool v = jl < 63;
        const float* src = TOKF + (size_t)(il * 63 + jl) * 64 + cc;
        uint16_t hh[16], lo[16];
#pragma unroll
        for (int u = 0; u < 16; u += 4) {
            float4 f = v ? *(const float4*)(src + u) : make_float4(0.f, 0.f, 0.f, 0.f);
            split_bf16(f.x, hh[u], lo[u]);     split_bf16(f.y, hh[u + 1], lo[u + 1]);
            split_bf16(f.z, hh[u + 2], lo[u + 2]); split_bf16(f.w, hh[u + 3], lo[u + 3]);
        }
        *(uint4*)&TFh[jl * 72 + cc] = pack8(hh); *(uint4*)&TFh[jl * 72 + cc + 8] = pack8(hh + 8);
        *(uint4*)&TFl[jl * 72 + cc] = pack8(lo); *(uint4*)&TFl[jl * 72 + cc + 8] = pack8(lo + 8);
    }

    float mrun[4] = {-1e30f, -1e30f, -1e30f, -1e30f};
    float drun[4] = {0.f, 0.f, 0.f, 0.f};
    f32x4 acc2[4];
#pragma unroll
    for (int ct = 0; ct < 4; ++ct) acc2[ct] = (f32x4)(0.f);

    int im0 = imc * IMR;
    int im1 = min(63, im0 + IMR);
    for (int im = im0; im < im1; ++im) {
        __syncthreads();
        {
            int jm = tid >> 2, cc = (tid & 3) * 16;
            bool v = jm < 63;
            const float* src = TOKB + (size_t)(im * 63 + jm) * 64 + cc;
            uint16_t hh[16], lo[16];
#pragma unroll
            for (int u = 0; u < 16; u += 4) {
                float4 f = v ? *(const float4*)(src + u) : make_float4(0.f, 0.f, 0.f, 0.f);
                split_bf16(f.x, hh[u], lo[u]);     split_bf16(f.y, hh[u + 1], lo[u + 1]);
                split_bf16(f.z, hh[u + 2], lo[u + 2]); split_bf16(f.w, hh[u + 3], lo[u + 3]);
            }
            *(uint4*)&TBh[jm * 72 + cc] = pack8(hh); *(uint4*)&TBh[jm * 72 + cc + 8] = pack8(hh + 8);
            *(uint4*)&TBl[jm * 72 + cc] = pack8(lo); *(uint4*)&TBl[jm * 72 + cc + 8] = pack8(lo + 8);
        }
        {
            int c = tid >> 2, mm = (tid & 3) * 16;
            const float* src = SBg + (size_t)c * LP + im * 63 + mm;
            uint16_t sv[16];
#pragma unroll
            for (int u = 0; u < 16; ++u)
                sv[u] = (mm + u < 63) ? bf16_rne(src[u]) : (uint16_t)0;
            *(uint4*)&SB[c * 72 + mm] = pack8(sv); *(uint4*)&SB[c * 72 + mm + 8] = pack8(sv + 8);
        }
        if (tid < 125) bias_r[tid] = rpb[(il - im + 62) * 125 + tid];
        else if (tid < 128) bias_r[tid] = 0.f;
        __syncthreads();

        f32x4 Z[4];
#pragma unroll
        for (int jt = 0; jt < 4; ++jt) Z[jt] = (f32x4)(0.f);
#pragma unroll
        for (int kk = 0; kk < 2; ++kk) {
            bf16x8 Ah = *(bf16x8*)&TFh[(w * 16 + c16) * 72 + kk * 32 + quad * 8];
            bf16x8 Al = *(bf16x8*)&TFl[(w * 16 + c16) * 72 + kk * 32 + quad * 8];
#pragma unroll
            for (int jt = 0; jt < 4; ++jt) {
                bf16x8 Bh = *(bf16x8*)&TBh[(jt * 16 + c16) * 72 + kk * 32 + quad * 8];
                bf16x8 Bl = *(bf16x8*)&TBl[(jt * 16 + c16) * 72 + kk * 32 + quad * 8];
                Z[jt] = __builtin_amdgcn_mfma_f32_16x16x32_bf16(Ah, Bh, Z[jt], 0, 0, 0);
                Z[jt] = __builtin_amdgcn_mfma_f32_16x16x32_bf16(Ah, Bl, Z[jt], 0, 0, 0);
                Z[jt] = __builtin_amdgcn_mfma_f32_16x16x32_bf16(Al, Bh, Z[jt], 0, 0, 0);
            }
        }
        float zv[4][4];
#pragma unroll
        for (int jt = 0; jt < 4; ++jt) {
            int jm = jt * 16 + c16;
#pragma unroll
            for (int r = 0; r < 4; ++r) {
                int i = w * 16 + quad * 4 + r;
                zv[jt][r] = (jm == 63) ? -1e30f : (Z[jt][r] + bias_r[i - jm + 62]);
            }
        }
        float alphav[4];
        uint16_t pb[4][4];
#pragma unroll
        for (int r = 0; r < 4; ++r) {
            float v = fmaxf(fmaxf(zv[0][r], zv[1][r]), fmaxf(zv[2][r], zv[3][r]));
            v = fmaxf(v, __shfl_xor(v, 1));
            v = fmaxf(v, __shfl_xor(v, 2));
            v = fmaxf(v, __shfl_xor(v, 4));
            v = fmaxf(v, __shfl_xor(v, 8));
            float mnew = fmaxf(mrun[r], v);
            alphav[r] = exp2f((mrun[r] - mnew) * LOG2E);
            float s = 0.f;
#pragma unroll
            for (int jt = 0; jt < 4; ++jt) {
                float p = exp2f((zv[jt][r] - mnew) * LOG2E);
                uint16_t h = bf16_rne(p);
                pb[jt][r] = h;
                s += __uint_as_float((uint32_t)h << 16);
            }
            s += __shfl_xor(s, 1); s += __shfl_xor(s, 2);
            s += __shfl_xor(s, 4); s += __shfl_xor(s, 8);
            drun[r] = drun[r] * alphav[r] + s;
            mrun[r] = mnew;
        }
#pragma unroll
        for (int ct = 0; ct < 4; ++ct)
#pragma unroll
            for (int r = 0; r < 4; ++r) acc2[ct][r] *= alphav[r];

        __syncthreads();
#pragma unroll
        for (int jt = 0; jt < 4; ++jt)
#pragma unroll
            for (int r = 0; r < 4; ++r)
                TBh[(w * 16 + quad * 4 + r) * 72 + jt * 16 + c16] = pb[jt][r];
        __syncthreads();

#pragma unroll
        for (int kk = 0; kk < 2; ++kk) {
            bf16x8 Pf = *(bf16x8*)&TBh[(w * 16 + c16) * 72 + kk * 32 + quad * 8];
#pragma unroll
            for (int ct = 0; ct < 4; ++ct) {
                bf16x8 Sf = *(bf16x8*)&SB[(ct * 16 + c16) * 72 + kk * 32 + quad * 8];
                acc2[ct] = __builtin_amdgcn_mfma_f32_16x16x32_bf16(Pf, Sf, acc2[ct], 0, 0, 0);
            }
        }
    }
    float* PA = ws + OFF_PACC + ((imc * 2 + b) * (size_t)LP) * 64;
#pragma unroll
    for (int r = 0; r < 4; ++r) {
        int i = w * 16 + quad * 4 + r;
        if (i < 63) {
            int rl = il * 63 + i;
#pragma unroll
            for (int ct = 0; ct < 4; ++ct)
                PA[(size_t)rl * 64 + ct * 16 + c16] = acc2[ct][r];
            if (c16 == 0) {
                ws[OFF_PM + (imc * 2 + b) * LP + rl] = mrun[r];
                ws[OFF_PD + (imc * 2 + b) * LP + rl] = drun[r];
            }
        }
    }
}

// ---------------- K3b: merge the MH m-slices; result lands in PACC slice 0 ----------------
__global__ void k3b_merge(float* __restrict__ ws) {
    int b = blockIdx.y;
    int l = blockIdx.x * 4 + (threadIdx.x >> 6);
    int c = threadIdx.x & 63;
    if (l >= L_) return;
    float M = -1e30f;
#pragma unroll
    for (int p = 0; p < MH; ++p)
        M = fmaxf(M, ws[OFF_PM + (p * 2 + b) * LP + l]);
    float denom = 0.f, num = 0.f;
#pragma unroll
    for (int p = 0; p < MH; ++p) {
        float w = exp2f((ws[OFF_PM + (p * 2 + b) * LP + l] - M) * LOG2E);
        denom += ws[OFF_PD + (p * 2 + b) * LP + l] * w;
        num += ws[OFF_PACC + ((p * 2 + b) * (size_t)LP + l) * 64 + c] * w;
    }
    ws[OFF_PACC + (b * (size_t)LP + l) * 64 + c] = num / denom;
}

// ---------------- K3c: fold coefficients A = NS/SF, B = NS - MF*A, C = NS*(MF+1) ----------------
// NS [b][l][c] (PACC slice 0) + MF/SF [b][c][LP]  ->  A/B/C in [b][c][LP] layout.
// Runs after k3b; writes into regions dead by then (TOKF/TOKB/PACC p=2).
__global__ void k3c_coef(float* __restrict__ ws) {
    int b = blockIdx.y;
    int bl = blockIdx.x;              // l0 = bl*4
    int tid = threadIdx.x;
    __shared__ float T[3][4][65];
    int ls = tid >> 6, c = tid & 63;
    int l = bl * 4 + ls;              // < LP always (993*4 = 3972)
    float ns = ws[OFF_PACC + ((size_t)b * LP + l) * 64 + c];
    float mf = ws[OFF_MF + (size_t)(b * 64 + c) * LP + l];
    float sf = ws[OFF_SF + (size_t)(b * 64 + c) * LP + l];
    float a = ns / sf;
    T[0][ls][c] = a;
    T[1][ls][c] = ns - mf * a;
    T[2][ls][c] = ns * (mf + 1.f);
    __syncthreads();
    int c2 = tid >> 2, l2 = tid & 3;
    size_t o = (size_t)(b * 64 + c2) * LP + bl * 4 + l2;
    ws[OFF_A + o] = T[0][l2][c2];
    ws[OFF_B + o] = T[1][l2][c2];
    ws[OFF_C + o] = T[2][l2][c2];
}

// ---------------- K4: fold + affines + compose output (coefficient form, no divides) ----------------
// Per pixel: covering patches are l00, l00+1, l00+63, l00+64 with validity flags.
// folded = m ? xv*SumA + SumB : SumC;   1/cnt via selects.
__global__ void k4_fold(const float* __restrict__ x, const float* __restrict__ mask,
                        const float* __restrict__ fg_g, const float* __restrict__ fg_b,
                        const float* __restrict__ bg_g, const float* __restrict__ bg_b,
                        const float* __restrict__ wsc, float* __restrict__ out) {
    int gid = blockIdx.x * 256 + threadIdx.x;
    int col = gid & 255, r = (gid >> 8) & 255, c = (gid >> 16) & 63, b = gid >> 22;
    float xv = x[gid];
    float m = mask[b * 65536 + r * 256 + col];
    int imin = (r >= 4) ? ((r - 4) >> 2) : 0;
    int imax = min(62, r >> 2);
    int jmin = (col >= 4) ? ((col - 4) >> 2) : 0;
    int jmax = min(62, col >> 2);
    bool fi = imax > imin, fj = jmax > jmin;
    int l00 = imin * 63 + jmin;
    const float* Aa = wsc + OFF_A + (size_t)(b * 64 + c) * LP;
    const float* Ba = wsc + OFF_B + (size_t)(b * 64 + c) * LP;
    const float* Ca = wsc + OFF_C + (size_t)(b * 64 + c) * LP;
    // unconditional loads (addresses stay inside workspace); selects discard invalid
    float a00 = Aa[l00],      b00 = Ba[l00],      c00 = Ca[l00];
    float a01 = Aa[l00 + 1],  b01 = Ba[l00 + 1],  c01 = Ca[l00 + 1];
    float a10 = Aa[l00 + 63], b10 = Ba[l00 + 63], c10 = Ca[l00 + 63];
    float a11 = Aa[l00 + 64], b11 = Ba[l00 + 64], c11 = Ca[l00 + 64];
    bool fij = fi && fj;
    float SA = a00 + (fj ? a01 : 0.f) + (fi ? a10 : 0.f) + (fij ? a11 : 0.f);
    float SBv = b00 + (fj ? b01 : 0.f) + (fi ? b10 : 0.f) + (fij ? b11 : 0.f);
    float SCv = c00 + (fj ? c01 : 0.f) + (fi ? c10 : 0.f) + (fij ? c11 : 0.f);
    float folded = (m != 0.f) ? (xv * SA + SBv) : SCv;
    float rc = (fi ? 0.5f : 1.f) * (fj ? 0.5f : 1.f);
    float invm = 1.f - m;
    float ub = (xv * invm * (1.f + bg_g[c]) + bg_b[c]) * invm;
    float nf = (folded * rc * (1.f + fg_g[c]) + fg_b[c]) * m;
    out[gid] = nf + ub;
}

extern "C" void kernel_launch(void* const* d_in, const int* in_sizes, int n_in,
                              void* d_out, int out_size, void* d_ws, size_t ws_size,
                              hipStream_t stream) {
    const float* x    = (const float*)d_in[0];
    const float* mask = (const float*)d_in[1];
    const float* fg_g = (const float*)d_in[2];
    const float* fg_b = (const float*)d_in[3];
    const float* bg_g = (const float*)d_in[4];
    const float* bg_b = (const float*)d_in[5];
    const float* wf   = (const float*)d_in[6];
    const float* wb   = (const float*)d_in[7];
    const float* rpb  = (const float*)d_in[8];
    float* ws = (float*)d_ws;
    float* out = (float*)d_out;

    k0_w2<<<dim3(64, 2), 256, 0, stream>>>(wf, wb, ws);
    k1_stats<<<dim3(63, 64, 2), 256, 0, stream>>>(x, mask, ws);
    k2_tok<<<dim3(63, 4, 2), 256, 0, stream>>>(x, mask, ws, ws);
    k2r_reduce<<<dim3(993), 256, 0, stream>>>(ws);
    k3_attn<<<dim3(63, MH, 2), 256, 0, stream>>>(ws, rpb, ws);
    k3b_merge<<<dim3(993, 2), 256, 0, stream>>>(ws);
    k3c_coef<<<dim3(993, 2), 256, 0, stream>>>(ws);
    k4_fold<<<dim3(32768), 256, 0, stream>>>(x, mask, fg_g, fg_b, bg_g, bg_b, ws, out);
}

// Round 3
// 258.004 us; speedup vs baseline: 1.2345x; 1.0181x over previous
//
#include <hip/hip_runtime.h>
#include <stdint.h>

// Problem constants
#define L_   3969         // patches
#define LP   3972         // padded L (mult of 4, for float4 loads)
#define EPS_ 1e-5f
#define LOG2E 1.4426950408889634f
#define MH   6            // split over im (patch-row chunks) in K3
#define IMR  11           // im rows per chunk (6*11 >= 63)

// workspace layout (float offsets). Total 6,720,608 floats = 26.9 MB
#define OFF_MF   0          // [2][64][LP] fg mean
#define OFF_SF   508416     // fg var
#define OFF_MB   1016832    // bg mean (dead after k2 -> reused for SB bf16 tiles by k1s)
#define OFF_SB   1525248    // bg var
#define OFF_TOKF 2033664    // [2 b][LP][64 c]; PART slice kc=0 (t=0 half); packed u32 after k2r
#define OFF_TOKB 2542080    //                 PART slice kc=0 (t=1 half)
#define OFF_PACC 3050496    // [MH][2 b][LP][64]; also PART slices kc=1..3 (dead until k3)
#define OFF_PM   6100992    // [MH][2][LP]
#define OFF_PD   6148656
#define OFF_WT   6196320    // W2: bf16 frag-ordered weights (1M bf16)
#define PART_SLICE 1016832  // floats per kc slice: [2 t][2 b][LP][64]

// fold coefficients (written by k3c AFTER k3b; these regions are dead by then)
#define OFF_A    2033664    // = OFF_TOKF  [2 b][64 c][LP]
#define OFF_B    2542080    // = OFF_TOKB
#define OFF_C    4067328    // = OFF_PACC + 2*508416 (PACC p=2 slice, dead after k3b)

typedef __attribute__((ext_vector_type(8))) short bf16x8;   // 8 bf16 (4 VGPRs)
typedef __attribute__((ext_vector_type(4))) float f32x4;    // MFMA accumulator

__device__ __forceinline__ uint16_t bf16_rne(float f) {
    uint32_t u = __float_as_uint(f);
    return (uint16_t)((u + 0x7FFFu + ((u >> 16) & 1u)) >> 16);
}
// hi = truncated top-16 bits (exact), lo = RNE(residual): hi+lo ~ 2^-17 relative
__device__ __forceinline__ void split_bf16(float v, uint16_t& h, uint16_t& l) {
    uint32_t u = __float_as_uint(v);
    uint32_t hu = u & 0xFFFF0000u;
    h = (uint16_t)(hu >> 16);
    l = bf16_rne(v - __uint_as_float(hu));
}
__device__ __forceinline__ uint4 pack8(const uint16_t* s) {
    uint4 r;
    r.x = (uint32_t)s[0] | ((uint32_t)s[1] << 16);
    r.y = (uint32_t)s[2] | ((uint32_t)s[3] << 16);
    r.z = (uint32_t)s[4] | ((uint32_t)s[5] << 16);
    r.w = (uint32_t)s[6] | ((uint32_t)s[7] << 16);
    return r;
}
// pair packers for the k2 fast path: elem a -> low16, elem b -> high16
__device__ __forceinline__ uint32_t pkhi2(float a, float b) {
    return (__float_as_uint(a) >> 16) | (__float_as_uint(b) & 0xFFFF0000u);
}
__device__ __forceinline__ uint32_t pklo2(float a, float b) {
    float ra = a - __uint_as_float(__float_as_uint(a) & 0xFFFF0000u);
    float rb = b - __uint_as_float(__float_as_uint(b) & 0xFFFF0000u);
    uint32_t r;
    asm("v_cvt_pk_bf16_f32 %0, %1, %2" : "=v"(r) : "v"(ra), "v"(rb));
    return r;
}
// de-interleave 16 packed (hi|lo<<16) u32 elements -> 2x uint4 hi-plane, 2x uint4 lo-plane
__device__ __forceinline__ void unpack16(const uint32_t* __restrict__ src,
                                         uint4* H, uint4* L) {
    uint4 e0 = *(const uint4*)(src);
    uint4 e1 = *(const uint4*)(src + 4);
    uint4 e2 = *(const uint4*)(src + 8);
    uint4 e3 = *(const uint4*)(src + 12);
    H[0].x = __builtin_amdgcn_perm(e0.y, e0.x, 0x05040100u);
    H[0].y = __builtin_amdgcn_perm(e0.w, e0.z, 0x05040100u);
    H[0].z = __builtin_amdgcn_perm(e1.y, e1.x, 0x05040100u);
    H[0].w = __builtin_amdgcn_perm(e1.w, e1.z, 0x05040100u);
    H[1].x = __builtin_amdgcn_perm(e2.y, e2.x, 0x05040100u);
    H[1].y = __builtin_amdgcn_perm(e2.w, e2.z, 0x05040100u);
    H[1].z = __builtin_amdgcn_perm(e3.y, e3.x, 0x05040100u);
    H[1].w = __builtin_amdgcn_perm(e3.w, e3.z, 0x05040100u);
    L[0].x = __builtin_amdgcn_perm(e0.y, e0.x, 0x07060302u);
    L[0].y = __builtin_amdgcn_perm(e0.w, e0.z, 0x07060302u);
    L[0].z = __builtin_amdgcn_perm(e1.y, e1.x, 0x07060302u);
    L[0].w = __builtin_amdgcn_perm(e1.w, e1.z, 0x07060302u);
    L[1].x = __builtin_amdgcn_perm(e2.y, e2.x, 0x07060302u);
    L[1].y = __builtin_amdgcn_perm(e2.w, e2.z, 0x07060302u);
    L[1].z = __builtin_amdgcn_perm(e3.y, e3.x, 0x07060302u);
    L[1].w = __builtin_amdgcn_perm(e3.w, e3.z, 0x07060302u);
}

// ---------------- K0: weights -> split-bf16 MFMA A-fragment layout ----------------
__global__ void k0_w2(const float* __restrict__ wf, const float* __restrict__ wb,
                      float* __restrict__ ws) {
    int c = blockIdx.x, t = blockIdx.y;
    const float* w = t ? wb : wf;
    uint16_t* w2 = (uint16_t*)(ws + OFF_WT);
    int tid = threadIdx.x;
    int lane = tid & 63, dq = tid >> 6;
    int d = dq * 16 + (lane & 15), quad = lane >> 4;
    for (int kci = 0; kci < 2; ++kci) {
        int k = kci * 32 + quad * 8;
        const float* src = w + (size_t)(d * 64 + c) * 64 + k;
        uint16_t hb[8], lb[8];
#pragma unroll
        for (int j = 0; j < 8; ++j) split_bf16(src[j], hb[j], lb[j]);
        size_t base = ((size_t)(((t * 64 + c) * 2 + kci) * 4 + dq) * 2) * 512 + lane * 8;
        *(uint4*)(w2 + base) = pack8(hb);
        *(uint4*)(w2 + base + 512) = pack8(lb);
    }
}

// ---------------- K1: per-patch fg/bg stats ----------------
__global__ void k1_stats(const float* __restrict__ x, const float* __restrict__ mask,
                         float* __restrict__ ws) {
    int i = blockIdx.x, c = blockIdx.y, b = blockIdx.z;
    __shared__ float xs[8 * 256];
    __shared__ float ms[8 * 256];
    __shared__ float pS[5][256];
    int t = threadIdx.x;
    const float* xr = x + (((b * 64 + c) * 256) + i * 4) * 256;
    const float* mr = mask + (b * 256 + i * 4) * 256;
#pragma unroll
    for (int r = 0; r < 8; ++r) {
        xs[r * 256 + t] = xr[r * 256 + t];
        ms[r * 256 + t] = mr[r * 256 + t];
    }
    __syncthreads();
    int q = t >> 6, j = t & 63;
    float Sa = 0, Qa = 0, Sf = 0, Qf = 0, Nf = 0;
    if (j < 63) {
#pragma unroll
        for (int rr = 0; rr < 2; ++rr) {
            int base = (q * 2 + rr) * 256 + j * 4;
#pragma unroll
            for (int cc = 0; cc < 8; ++cc) {
                float v = xs[base + cc], m = ms[base + cc];
                Sa += v; Qa += v * v; Sf += v * m; Qf += v * v * m; Nf += m;
            }
        }
    }
    pS[0][t] = Sa; pS[1][t] = Qa; pS[2][t] = Sf; pS[3][t] = Qf; pS[4][t] = Nf;
    __syncthreads();
    if (q == 0 && j < 63) {
        Sa = pS[0][j] + pS[0][j + 64] + pS[0][j + 128] + pS[0][j + 192];
        Qa = pS[1][j] + pS[1][j + 64] + pS[1][j + 128] + pS[1][j + 192];
        Sf = pS[2][j] + pS[2][j + 64] + pS[2][j + 128] + pS[2][j + 192];
        Qf = pS[3][j] + pS[3][j + 64] + pS[3][j + 128] + pS[3][j + 192];
        Nf = pS[4][j] + pS[4][j + 64] + pS[4][j + 128] + pS[4][j + 192];
        float nb = 64.0f - Nf;
        float muf = Sf / (Nf + EPS_);
        float vaf = (Qf - 2.f * muf * Sf + Nf * muf * muf) / (Nf + EPS_);
        float Sb = Sa - Sf, Qb = Qa - Qf;
        float mub = Sb / (nb + EPS_);
        float vab = (Qb - 2.f * mub * Sb + nb * mub * mub) / (nb + EPS_);
        int idx = (b * 64 + c) * LP + i * 63 + j;
        ws[OFF_MF + idx] = muf; ws[OFF_SF + idx] = vaf;
        ws[OFF_MB + idx] = mub; ws[OFF_SB + idx] = vab;
    }
}

// ---------------- K2: split-bf16 MFMA tok GEMM ----------------
// Single-channel double-buffered pipeline (1 barrier/channel),
// 2x2 wave->(d,l) tile split, cvt_pk-based packing.
// grid (63 il, 4 kc, 2 b), 256 threads. LDS 72 KB -> 2 blocks/CU.
__global__ __launch_bounds__(256)
void k2_tok(const float* __restrict__ x, const float* __restrict__ mask,
            const float* __restrict__ wsc, float* __restrict__ ws) {
    int il = blockIdx.x, kc = blockIdx.y, b = blockIdx.z;
    int tid = threadIdx.x;
    int jl = tid & 63;
    int q = tid >> 6;
    __shared__ uint16_t IN[2][4 * 64 * 72];   // [buffer][plane 4][l 64][k 72pad]
    const uint16_t* w2 = (const uint16_t*)(wsc + OFF_WT);

    bool lv = jl < 63;
    int lg = il * 63 + jl;

    uint32_t mbits[2] = {0u, 0u};
    if (lv) {
#pragma unroll
        for (int oi = 0; oi < 2; ++oi) {
            int o = q + oi * 4;
            const float* mp = mask + (size_t)b * 65536 + (il * 4 + o) * 256 + jl * 4;
            float4 m0 = *(const float4*)mp;
            float4 m1 = *(const float4*)(mp + 4);
            uint32_t bits = 0;
            bits |= (m0.x != 0.f) ? 1u : 0u;  bits |= (m0.y != 0.f) ? 2u : 0u;
            bits |= (m0.z != 0.f) ? 4u : 0u;  bits |= (m0.w != 0.f) ? 8u : 0u;
            bits |= (m1.x != 0.f) ? 16u : 0u; bits |= (m1.y != 0.f) ? 32u : 0u;
            bits |= (m1.z != 0.f) ? 64u : 0u; bits |= (m1.w != 0.f) ? 128u : 0u;
            mbits[oi] = bits;
        }
    }

    f32x4 acc[2][2][2];   // [t][dqi][lt]
#pragma unroll
    for (int t = 0; t < 2; ++t)
#pragma unroll
        for (int i2 = 0; i2 < 2; ++i2)
#pragma unroll
            for (int j2 = 0; j2 < 2; ++j2) acc[t][i2][j2] = (f32x4)(0.f);

    int lane = tid & 63;
    int quad = lane >> 4;
    int c16 = lane & 15;
    int wd = q >> 1, wl = q & 1;   // wave tile: d half, l half
    int c0 = kc * 16;

    // pipeline registers: one channel
    float4 xa[2][2];   // [oi][half]
    if (!lv) {
        xa[0][0] = xa[0][1] = xa[1][0] = xa[1][1] = make_float4(0.f, 0.f, 0.f, 0.f);
    }
    float muF = 0.f, vaF = 1.f, muB = 0.f, vaB = 1.f;

#define K2_LOADCH(cc)                                                                \
    do {                                                                             \
        if (lv) {                                                                    \
            int si = (b * 64 + (cc)) * LP + lg;                                      \
            muF = wsc[OFF_MF + si]; vaF = wsc[OFF_SF + si];                          \
            muB = wsc[OFF_MB + si]; vaB = wsc[OFF_SB + si];                          \
            const float* xp0 = x + (size_t)(b * 64 + (cc)) * 65536 + (il * 4 + q) * 256 + jl * 4; \
            xa[0][0] = *(const float4*)xp0;                                          \
            xa[0][1] = *(const float4*)(xp0 + 4);                                    \
            xa[1][0] = *(const float4*)(xp0 + 1024);                                 \
            xa[1][1] = *(const float4*)(xp0 + 1028);                                 \
        }                                                                            \
    } while (0)

    // pack current xa/stats into buffer 'bufsel'. For jl==63 lanes: mbits==0,
    // cmF/cmB/invF/invB == 0 and xa == 0 -> all staged values are exactly 0.
#define K2_PACKSTORE(bufsel)                                                         \
    do {                                                                             \
        float invF = lv ? (1.0f / vaF) : 0.f;                                        \
        float invB = lv ? (1.0f / vaB) : 0.f;                                        \
        float cmF = lv ? muF : 0.f;                                                  \
        float cmB = lv ? muB : 0.f;                                                  \
        _Pragma("unroll")                                                            \
        for (int oi = 0; oi < 2; ++oi) {                                             \
            float xv[8];                                                             \
            xv[0] = xa[oi][0].x; xv[1] = xa[oi][0].y;                                \
            xv[2] = xa[oi][0].z; xv[3] = xa[oi][0].w;                                \
            xv[4] = xa[oi][1].x; xv[5] = xa[oi][1].y;                                \
            xv[6] = xa[oi][1].z; xv[7] = xa[oi][1].w;                                \
            float fv[8], bv[8];                                                      \
            _Pragma("unroll")                                                        \
            for (int j = 0; j < 8; ++j) {                                            \
                bool mf = (mbits[oi] >> j) & 1;                                      \
                float v = xv[j];                                                     \
                fv[j] = mf ? (v - cmF) * invF : cmF;                                 \
                bv[j] = mf ? cmB : (v - cmB) * invB;                                 \
            }                                                                        \
            uint4 FH, FL, BH, BL;                                                    \
            FH.x = pkhi2(fv[0], fv[1]); FH.y = pkhi2(fv[2], fv[3]);                  \
            FH.z = pkhi2(fv[4], fv[5]); FH.w = pkhi2(fv[6], fv[7]);                  \
            FL.x = pklo2(fv[0], fv[1]); FL.y = pklo2(fv[2], fv[3]);                  \
            FL.z = pklo2(fv[4], fv[5]); FL.w = pklo2(fv[6], fv[7]);                  \
            BH.x = pkhi2(bv[0], bv[1]); BH.y = pkhi2(bv[2], bv[3]);                  \
            BH.z = pkhi2(bv[4], bv[5]); BH.w = pkhi2(bv[6], bv[7]);                  \
            BL.x = pklo2(bv[0], bv[1]); BL.y = pklo2(bv[2], bv[3]);                  \
            BL.z = pklo2(bv[4], bv[5]); BL.w = pklo2(bv[6], bv[7]);                  \
            uint16_t* dst = &IN[bufsel][jl * 72 + (q + oi * 4) * 8];                 \
            *(uint4*)(dst)         = FH;                                             \
            *(uint4*)(dst + 4608)  = FL;                                             \
            *(uint4*)(dst + 9216)  = BH;                                             \
            *(uint4*)(dst + 13824) = BL;                                             \
        }                                                                            \
    } while (0)

    // MFMA over one staged channel. Wave covers d in [wd*32, wd*32+32),
    // l in [wl*32, wl*32+32). A frags reused across both l-tiles.
#define K2_MFMA(bufi, cch)                                                           \
    do {                                                                             \
        _Pragma("unroll")                                                            \
        for (int t = 0; t < 2; ++t) {                                                \
            _Pragma("unroll")                                                        \
            for (int kci = 0; kci < 2; ++kci) {                                      \
                bf16x8 Ah[2], Al[2];                                                 \
                _Pragma("unroll")                                                    \
                for (int dqi = 0; dqi < 2; ++dqi) {                                  \
                    const uint16_t* ab = w2 +                                        \
                        ((size_t)(((t * 64 + (cch)) * 2 + kci) * 4 + (wd * 2 + dqi)) * 2) * 512 + lane * 8; \
                    Ah[dqi] = *(const bf16x8*)ab;                                    \
                    Al[dqi] = *(const bf16x8*)(ab + 512);                            \
                }                                                                    \
                _Pragma("unroll")                                                    \
                for (int lt = 0; lt < 2; ++lt) {                                     \
                    const uint16_t* bp = &IN[bufi][(t * 2) * 4608 +                  \
                        (wl * 32 + lt * 16 + c16) * 72 + kci * 32 + quad * 8];       \
                    bf16x8 Bh = *(const bf16x8*)bp;                                  \
                    bf16x8 Bl = *(const bf16x8*)(bp + 4608);                         \
                    _Pragma("unroll")                                                \
                    for (int dqi = 0; dqi < 2; ++dqi) {                              \
                        acc[t][dqi][lt] = __builtin_amdgcn_mfma_f32_16x16x32_bf16(Ah[dqi], Bh, acc[t][dqi][lt], 0, 0, 0); \
                        acc[t][dqi][lt] = __builtin_amdgcn_mfma_f32_16x16x32_bf16(Ah[dqi], Bl, acc[t][dqi][lt], 0, 0, 0); \
                        acc[t][dqi][lt] = __builtin_amdgcn_mfma_f32_16x16x32_bf16(Al[dqi], Bh, acc[t][dqi][lt], 0, 0, 0); \
                    }                                                                \
                }                                                                    \
            }                                                                        \
        }                                                                            \
    } while (0)

    // prologue: stage channel c0 into buffer 0, prefetch c0+1
    K2_LOADCH(c0);
    K2_PACKSTORE(0);
    K2_LOADCH(c0 + 1);
    __syncthreads();

    // steady state: one barrier per channel. Writes go to buffer cur^1 whose
    // readers all finished before the previous barrier; reads come from cur.
#pragma unroll 2
    for (int ci = 0; ci < 16; ++ci) {
        int cur = ci & 1;
        if (ci < 15) {
            K2_PACKSTORE(cur ^ 1);             // pack channel ci+1
            if (ci < 14) K2_LOADCH(c0 + ci + 2); // issue global loads for ci+2
        }
        K2_MFMA(cur, c0 + ci);
        __syncthreads();
    }
#undef K2_LOADCH
#undef K2_PACKSTORE
#undef K2_MFMA

    // ---- epilogue: LDS transpose -> coalesced float4 stores to PART (no atomics) ----
    // C/D 16x16: row(d within tile)=quad*4+r, col(l within tile)=lane&15
    float* ST = (float*)&IN[0][0];   // 64 l x 68 d floats = 17.4 KB, fits
#pragma unroll
    for (int t = 0; t < 2; ++t) {
        __syncthreads();
#pragma unroll
        for (int dqi = 0; dqi < 2; ++dqi)
#pragma unroll
            for (int lt = 0; lt < 2; ++lt)
#pragma unroll
                for (int r = 0; r < 4; ++r)
                    ST[(wl * 32 + lt * 16 + c16) * 68 + (wd * 2 + dqi) * 16 + quad * 4 + r] =
                        acc[t][dqi][lt][r];
        __syncthreads();
        float* dst = ws + OFF_TOKF + (size_t)kc * PART_SLICE + ((t * 2 + b) * (size_t)LP) * 64;
        int d4 = (tid & 15) * 4;
#pragma unroll
        for (int pass = 0; pass < 4; ++pass) {
            int l = pass * 16 + (tid >> 4);
            if (l < 63)
                *(float4*)&dst[(size_t)(il * 63 + l) * 64 + d4] = *(float4*)&ST[l * 68 + d4];
        }
    }
}

// ---------------- K2r: reduce 4 kc partial slices into slice 0, packing to split-bf16 ----
// Output element = u32 (hi | lo<<16) written in place of the f32 (race-free: same slot).
__global__ void k2r_reduce(float* __restrict__ ws) {
    size_t i = ((size_t)blockIdx.x * 256 + threadIdx.x) * 4;
    float4 a0 = *(float4*)&ws[OFF_TOKF + i];
    float4 a1 = *(float4*)&ws[OFF_TOKF + PART_SLICE + i];
    float4 a2 = *(float4*)&ws[OFF_TOKF + 2 * PART_SLICE + i];
    float4 a3 = *(float4*)&ws[OFF_TOKF + 3 * PART_SLICE + i];
    float s0 = a0.x + a1.x + a2.x + a3.x;
    float s1 = a0.y + a1.y + a2.y + a3.y;
    float s2 = a0.z + a1.z + a2.z + a3.z;
    float s3 = a0.w + a1.w + a2.w + a3.w;
    uint16_t h, l;
    uint4 o;
    split_bf16(s0, h, l); o.x = (uint32_t)h | ((uint32_t)l << 16);
    split_bf16(s1, h, l); o.y = (uint32_t)h | ((uint32_t)l << 16);
    split_bf16(s2, h, l); o.z = (uint32_t)h | ((uint32_t)l << 16);
    split_bf16(s3, h, l); o.w = (uint32_t)h | ((uint32_t)l << 16);
    *(uint4*)&ws[OFF_TOKF + i] = o;
}

// ---------------- K1s: SB variances -> bf16 tiles [b][im][c][64] (m=63 zeroed) ----------
// Written into the dead MB region. Runs after k2 (last reader of MB/SB f32 pair layout).
__global__ void k1s_sb(float* __restrict__ ws) {
    int im = blockIdx.x, b = blockIdx.y;
    int tid = threadIdx.x;
    int c = tid >> 2, mm = (tid & 3) * 16;
    const float* src = ws + OFF_SB + ((size_t)b * 64 + c) * LP + im * 63 + mm;
    uint16_t sv[16];
#pragma unroll
    for (int u = 0; u < 16; ++u)
        sv[u] = (mm + u < 63) ? bf16_rne(src[u]) : (uint16_t)0;
    uint16_t* dst = (uint16_t*)(ws + OFF_MB) + (((size_t)b * 63 + im) * 64 + c) * 64 + mm;
    *(uint4*)(dst) = pack8(sv);
    *(uint4*)(dst + 8) = pack8(sv + 8);
}

// ---------------- K3: MFMA flash attention over patch-rows ----------------
// grid (63 il, MH imc, 2 b), 256 threads. Staging is now pure copy+perm
// (tok pre-split by k2r into packed u32; SB pre-converted by k1s).
__global__ __launch_bounds__(256)
void k3_attn(const float* __restrict__ wsc, const float* __restrict__ rpb,
             float* __restrict__ ws) {
    int il = blockIdx.x, imc = blockIdx.y, b = blockIdx.z;
    int tid = threadIdx.x;
    int w = tid >> 6, lane = tid & 63;
    int c16 = lane & 15, quad = lane >> 4;

    __shared__ uint16_t TFh[64 * 72], TFl[64 * 72];   // tok_f [l][c] hi/lo
    __shared__ uint16_t TBh[64 * 72];                 // tok_b hi [m][c]; aliased as P [l][m]
    __shared__ uint16_t TBl[64 * 72];                 // tok_b lo
    __shared__ uint16_t SB[64 * 72];                  // sb [c][m] bf16
    __shared__ float bias_r[128];

    const uint32_t* TOKP = (const uint32_t*)(wsc + OFF_TOKF);
    const uint32_t* TF32 = TOKP + (size_t)b * LP * 64;         // t=0 plane (packed hi|lo)
    const uint32_t* TB32 = TOKP + (size_t)(2 + b) * LP * 64;   // t=1 plane
    const uint16_t* sbb  = (const uint16_t*)(wsc + OFF_MB);    // [b][im][c][64] bf16

    {
        int jl2 = tid >> 2, cc = (tid & 3) * 16;
        uint4 H[2], L[2];
        if (jl2 < 63) {
            unpack16(TF32 + (size_t)(il * 63 + jl2) * 64 + cc, H, L);
        } else {
            H[0] = H[1] = L[0] = L[1] = make_uint4(0u, 0u, 0u, 0u);
        }
        *(uint4*)&TFh[jl2 * 72 + cc] = H[0]; *(uint4*)&TFh[jl2 * 72 + cc + 8] = H[1];
        *(uint4*)&TFl[jl2 * 72 + cc] = L[0]; *(uint4*)&TFl[jl2 * 72 + cc + 8] = L[1];
    }

    float mrun[4] = {-1e30f, -1e30f, -1e30f, -1e30f};
    float drun[4] = {0.f, 0.f, 0.f, 0.f};
    f32x4 acc2[4];
#pragma unroll
    for (int ct = 0; ct < 4; ++ct) acc2[ct] = (f32x4)(0.f);

    int im0 = imc * IMR;
    int im1 = min(63, im0 + IMR);
    for (int im = im0; im < im1; ++im) {
        __syncthreads();
        {
            int jm = tid >> 2, cc = (tid & 3) * 16;
            uint4 H[2], L[2];
            if (jm < 63) {
                unpack16(TB32 + (size_t)(im * 63 + jm) * 64 + cc, H, L);
            } else {
                H[0] = H[1] = L[0] = L[1] = make_uint4(0u, 0u, 0u, 0u);
            }
            *(uint4*)&TBh[jm * 72 + cc] = H[0]; *(uint4*)&TBh[jm * 72 + cc + 8] = H[1];
            *(uint4*)&TBl[jm * 72 + cc] = L[0]; *(uint4*)&TBl[jm * 72 + cc + 8] = L[1];
        }
        {
            int c = tid >> 2, mm = (tid & 3) * 16;
            const uint16_t* src = sbb + (((size_t)b * 63 + im) * 64 + c) * 64 + mm;
            uint4 v0 = *(const uint4*)src;
            uint4 v1 = *(const uint4*)(src + 8);
            *(uint4*)&SB[c * 72 + mm] = v0; *(uint4*)&SB[c * 72 + mm + 8] = v1;
        }
        if (tid < 125) bias_r[tid] = rpb[(il - im + 62) * 125 + tid];
        else if (tid < 128) bias_r[tid] = 0.f;
        __syncthreads();

        f32x4 Z[4];
#pragma unroll
        for (int jt = 0; jt < 4; ++jt) Z[jt] = (f32x4)(0.f);
#pragma unroll
        for (int kk = 0; kk < 2; ++kk) {
            bf16x8 Ah = *(bf16x8*)&TFh[(w * 16 + c16) * 72 + kk * 32 + quad * 8];
            bf16x8 Al = *(bf16x8*)&TFl[(w * 16 + c16) * 72 + kk * 32 + quad * 8];
#pragma unroll
            for (int jt = 0; jt < 4; ++jt) {
                bf16x8 Bh = *(bf16x8*)&TBh[(jt * 16 + c16) * 72 + kk * 32 + quad * 8];
                bf16x8 Bl = *(bf16x8*)&TBl[(jt * 16 + c16) * 72 + kk * 32 + quad * 8];
                Z[jt] = __builtin_amdgcn_mfma_f32_16x16x32_bf16(Ah, Bh, Z[jt], 0, 0, 0);
                Z[jt] = __builtin_amdgcn_mfma_f32_16x16x32_bf16(Ah, Bl, Z[jt], 0, 0, 0);
                Z[jt] = __builtin_amdgcn_mfma_f32_16x16x32_bf16(Al, Bh, Z[jt], 0, 0, 0);
            }
        }
        float zv[4][4];
#pragma unroll
        for (int jt = 0; jt < 4; ++jt) {
            int jm = jt * 16 + c16;
#pragma unroll
            for (int r = 0; r < 4; ++r) {
                int i = w * 16 + quad * 4 + r;
                zv[jt][r] = (jm == 63) ? -1e30f : (Z[jt][r] + bias_r[i - jm + 62]);
            }
        }
        float alphav[4];
        uint16_t pb[4][4];
#pragma unroll
        for (int r = 0; r < 4; ++r) {
            float v = fmaxf(fmaxf(zv[0][r], zv[1][r]), fmaxf(zv[2][r], zv[3][r]));
            v = fmaxf(v, __shfl_xor(v, 1));
            v = fmaxf(v, __shfl_xor(v, 2));
            v = fmaxf(v, __shfl_xor(v, 4));
            v = fmaxf(v, __shfl_xor(v, 8));
            float mnew = fmaxf(mrun[r], v);
            alphav[r] = exp2f((mrun[r] - mnew) * LOG2E);
            float s = 0.f;
#pragma unroll
            for (int jt = 0; jt < 4; ++jt) {
                float p = exp2f((zv[jt][r] - mnew) * LOG2E);
                uint16_t h = bf16_rne(p);
                pb[jt][r] = h;
                s += __uint_as_float((uint32_t)h << 16);
            }
            s += __shfl_xor(s, 1); s += __shfl_xor(s, 2);
            s += __shfl_xor(s, 4); s += __shfl_xor(s, 8);
            drun[r] = drun[r] * alphav[r] + s;
            mrun[r] = mnew;
        }
#pragma unroll
        for (int ct = 0; ct < 4; ++ct)
#pragma unroll
            for (int r = 0; r < 4; ++r) acc2[ct][r] *= alphav[r];

        __syncthreads();
#pragma unroll
        for (int jt = 0; jt < 4; ++jt)
#pragma unroll
            for (int r = 0; r < 4; ++r)
                TBh[(w * 16 + quad * 4 + r) * 72 + jt * 16 + c16] = pb[jt][r];
        __syncthreads();

#pragma unroll
        for (int kk = 0; kk < 2; ++kk) {
            bf16x8 Pf = *(bf16x8*)&TBh[(w * 16 + c16) * 72 + kk * 32 + quad * 8];
#pragma unroll
            for (int ct = 0; ct < 4; ++ct) {
                bf16x8 Sf = *(bf16x8*)&SB[(ct * 16 + c16) * 72 + kk * 32 + quad * 8];
                acc2[ct] = __builtin_amdgcn_mfma_f32_16x16x32_bf16(Pf, Sf, acc2[ct], 0, 0, 0);
            }
        }
    }
    float* PA = ws + OFF_PACC + ((imc * 2 + b) * (size_t)LP) * 64;
#pragma unroll
    for (int r = 0; r < 4; ++r) {
        int i = w * 16 + quad * 4 + r;
        if (i < 63) {
            int rl = il * 63 + i;
#pragma unroll
            for (int ct = 0; ct < 4; ++ct)
                PA[(size_t)rl * 64 + ct * 16 + c16] = acc2[ct][r];
            if (c16 == 0) {
                ws[OFF_PM + (imc * 2 + b) * LP + rl] = mrun[r];
                ws[OFF_PD + (imc * 2 + b) * LP + rl] = drun[r];
            }
        }
    }
}

// ---------------- K3b: merge the MH m-slices; result lands in PACC slice 0 ----------------
__global__ void k3b_merge(float* __restrict__ ws) {
    int b = blockIdx.y;
    int l = blockIdx.x * 4 + (threadIdx.x >> 6);
    int c = threadIdx.x & 63;
    if (l >= L_) return;
    float M = -1e30f;
#pragma unroll
    for (int p = 0; p < MH; ++p)
        M = fmaxf(M, ws[OFF_PM + (p * 2 + b) * LP + l]);
    float denom = 0.f, num = 0.f;
#pragma unroll
    for (int p = 0; p < MH; ++p) {
        float w = exp2f((ws[OFF_PM + (p * 2 + b) * LP + l] - M) * LOG2E);
        denom += ws[OFF_PD + (p * 2 + b) * LP + l] * w;
        num += ws[OFF_PACC + ((p * 2 + b) * (size_t)LP + l) * 64 + c] * w;
    }
    ws[OFF_PACC + (b * (size_t)LP + l) * 64 + c] = num / denom;
}

// ---------------- K3c: fold coefficients A = NS/SF, B = NS - MF*A, C = NS*(MF+1) ----------------
// NS [b][l][c] (PACC slice 0) + MF/SF [b][c][LP]  ->  A/B/C in [b][c][LP] layout.
// Runs after k3b; writes into regions dead by then (TOKF/TOKB/PACC p=2).
__global__ void k3c_coef(float* __restrict__ ws) {
    int b = blockIdx.y;
    int bl = blockIdx.x;              // l0 = bl*4
    int tid = threadIdx.x;
    __shared__ float T[3][4][65];
    int ls = tid >> 6, c = tid & 63;
    int l = bl * 4 + ls;              // < LP always (993*4 = 3972)
    float ns = ws[OFF_PACC + ((size_t)b * LP + l) * 64 + c];
    float mf = ws[OFF_MF + (size_t)(b * 64 + c) * LP + l];
    float sf = ws[OFF_SF + (size_t)(b * 64 + c) * LP + l];
    float a = ns / sf;
    T[0][ls][c] = a;
    T[1][ls][c] = ns - mf * a;
    T[2][ls][c] = ns * (mf + 1.f);
    __syncthreads();
    int c2 = tid >> 2, l2 = tid & 3;
    size_t o = (size_t)(b * 64 + c2) * LP + bl * 4 + l2;
    ws[OFF_A + o] = T[0][l2][c2];
    ws[OFF_B + o] = T[1][l2][c2];
    ws[OFF_C + o] = T[2][l2][c2];
}

// ---------------- K4: fold + affines + compose output (coefficient form, no divides) ----------------
// Per pixel: covering patches are l00, l00+1, l00+63, l00+64 with validity flags.
// folded = m ? xv*SumA + SumB : SumC;   1/cnt via selects.
__global__ void k4_fold(const float* __restrict__ x, const float* __restrict__ mask,
                        const float* __restrict__ fg_g, const float* __restrict__ fg_b,
                        const float* __restrict__ bg_g, const float* __restrict__ bg_b,
                        const float* __restrict__ wsc, float* __restrict__ out) {
    int gid = blockIdx.x * 256 + threadIdx.x;
    int col = gid & 255, r = (gid >> 8) & 255, c = (gid >> 16) & 63, b = gid >> 22;
    float xv = x[gid];
    float m = mask[b * 65536 + r * 256 + col];
    int imin = (r >= 4) ? ((r - 4) >> 2) : 0;
    int imax = min(62, r >> 2);
    int jmin = (col >= 4) ? ((col - 4) >> 2) : 0;
    int jmax = min(62, col >> 2);
    bool fi = imax > imin, fj = jmax > jmin;
    int l00 = imin * 63 + jmin;
    const float* Aa = wsc + OFF_A + (size_t)(b * 64 + c) * LP;
    const float* Ba = wsc + OFF_B + (size_t)(b * 64 + c) * LP;
    const float* Ca = wsc + OFF_C + (size_t)(b * 64 + c) * LP;
    // unconditional loads (addresses stay inside workspace); selects discard invalid
    float a00 = Aa[l00],      b00 = Ba[l00],      c00 = Ca[l00];
    float a01 = Aa[l00 + 1],  b01 = Ba[l00 + 1],  c01 = Ca[l00 + 1];
    float a10 = Aa[l00 + 63], b10 = Ba[l00 + 63], c10 = Ca[l00 + 63];
    float a11 = Aa[l00 + 64], b11 = Ba[l00 + 64], c11 = Ca[l00 + 64];
    bool fij = fi && fj;
    float SA = a00 + (fj ? a01 : 0.f) + (fi ? a10 : 0.f) + (fij ? a11 : 0.f);
    float SBv = b00 + (fj ? b01 : 0.f) + (fi ? b10 : 0.f) + (fij ? b11 : 0.f);
    float SCv = c00 + (fj ? c01 : 0.f) + (fi ? c10 : 0.f) + (fij ? c11 : 0.f);
    float folded = (m != 0.f) ? (xv * SA + SBv) : SCv;
    float rc = (fi ? 0.5f : 1.f) * (fj ? 0.5f : 1.f);
    float invm = 1.f - m;
    float ub = (xv * invm * (1.f + bg_g[c]) + bg_b[c]) * invm;
    float nf = (folded * rc * (1.f + fg_g[c]) + fg_b[c]) * m;
    out[gid] = nf + ub;
}

extern "C" void kernel_launch(void* const* d_in, const int* in_sizes, int n_in,
                              void* d_out, int out_size, void* d_ws, size_t ws_size,
                              hipStream_t stream) {
    const float* x    = (const float*)d_in[0];
    const float* mask = (const float*)d_in[1];
    const float* fg_g = (const float*)d_in[2];
    const float* fg_b = (const float*)d_in[3];
    const float* bg_g = (const float*)d_in[4];
    const float* bg_b = (const float*)d_in[5];
    const float* wf   = (const float*)d_in[6];
    const float* wb   = (const float*)d_in[7];
    const float* rpb  = (const float*)d_in[8];
    float* ws = (float*)d_ws;
    float* out = (float*)d_out;

    k0_w2<<<dim3(64, 2), 256, 0, stream>>>(wf, wb, ws);
    k1_stats<<<dim3(63, 64, 2), 256, 0, stream>>>(x, mask, ws);
    k2_tok<<<dim3(63, 4, 2), 256, 0, stream>>>(x, mask, ws, ws);
    k2r_reduce<<<dim3(993), 256, 0, stream>>>(ws);
    k1s_sb<<<dim3(63, 2), 256, 0, stream>>>(ws);
    k3_attn<<<dim3(63, MH, 2), 256, 0, stream>>>(ws, rpb, ws);
    k3b_merge<<<dim3(993, 2), 256, 0, stream>>>(ws);
    k3c_coef<<<dim3(993, 2), 256, 0, stream>>>(ws);
    k4_fold<<<dim3(32768), 256, 0, stream>>>(x, mask, fg_g, fg_b, bg_g, bg_b, ws, out);
}